// Round 17
// baseline (209.138 us; speedup 1.0000x reference)
//
#include <hip/hip_runtime.h>

// VQ nearest-codeword, 2-tier (round-8 kernels, dispatch-fused):
//  fused_pack: memset(cnt) + pack_x + pack_e + pack_et in ONE dispatch.
//  T1 vq_main: fp16 single-pass MFMA GEMM, fused per-row top-2 (proven).
//  T2: vq_exact_part (ET-coalesced partial argmin, 8 rows/group halves
//      redundant ET traffic) + vq_combine2 (combine partials + overflow).

typedef float f32x4 __attribute__((ext_vector_type(4)));
typedef _Float16 f16x8 __attribute__((ext_vector_type(8)));

#define TAU1 0.15f
#define LIST_CAP 65536u
#define PROWS 4096u

struct Part { double d; long long idx; };  // 16 B

__device__ __forceinline__ unsigned short f16b(float f) {
  _Float16 h = (_Float16)f;
  return __builtin_bit_cast(unsigned short, h);
}

__device__ __forceinline__ void gl16(char* lds, const char* g) {
  __builtin_amdgcn_global_load_lds(
      (const __attribute__((address_space(1))) void*)g,
      (__attribute__((address_space(3))) void*)lds, 16, 0, 0);
}

// ---- fused pack: blocks [0,2048) pack_x, [2048,2304) pack_e (+cnt zero),
//      [2304,2560) pack_et (skipped when has_et==0) ----
__global__ __launch_bounds__(256) void fused_pack(
    const float* __restrict__ x, char* xp, const float* __restrict__ E,
    char* __restrict__ ehi, float* __restrict__ e2f, double* __restrict__ e2d,
    float* __restrict__ ET, int has_et, unsigned* __restrict__ cnt1) {
  const int bx = blockIdx.x;
  const int tid = threadIdx.x;
  if (bx < 2048) {  // ---- pack_x body (proven) ----
    int gid = bx * 256 + tid;
    int row = gid >> 4, seg = gid & 15;
    const float4* xr = (const float4*)(x + (size_t)row * 256 + seg * 16);
    unsigned o[8];
#pragma unroll
    for (int q = 0; q < 4; ++q) {
      float4 f = xr[q];
      o[q * 2]     = (unsigned)f16b(f.x) | ((unsigned)f16b(f.y) << 16);
      o[q * 2 + 1] = (unsigned)f16b(f.z) | ((unsigned)f16b(f.w) << 16);
    }
    uint4* dst = (uint4*)(xp + (size_t)row * 1024 + seg * 32);
    dst[0] = make_uint4(o[0], o[1], o[2], o[3]);
    dst[1] = make_uint4(o[4], o[5], o[6], o[7]);
  } else if (bx < 2304) {  // ---- pack_e body (proven) + cnt zero ----
    if (bx == 2048 && tid == 0) *cnt1 = 0u;
    int vl = tid >> 4, seg = tid & 15;
    int v = (bx - 2048) * 16 + vl;
    const float4* er = (const float4*)(E + (size_t)v * 256 + seg * 16);
    unsigned oh[8];
    double s = 0.0;
#pragma unroll
    for (int q = 0; q < 4; ++q) {
      float4 f = er[q];
      float vf[4] = {f.x, f.y, f.z, f.w};
      unsigned short hb[4];
#pragma unroll
      for (int e = 0; e < 4; ++e) {
        float fv = vf[e];
        s += (double)fv * (double)fv;
        hb[e] = f16b(fv);
      }
      oh[q * 2]     = (unsigned)hb[0] | ((unsigned)hb[1] << 16);
      oh[q * 2 + 1] = (unsigned)hb[2] | ((unsigned)hb[3] << 16);
    }
    uint4* dh = (uint4*)(ehi + (size_t)v * 512 + seg * 32);
    dh[0] = make_uint4(oh[0], oh[1], oh[2], oh[3]);
    dh[1] = make_uint4(oh[4], oh[5], oh[6], oh[7]);
#pragma unroll
    for (int off = 1; off < 16; off <<= 1) s += __shfl_xor(s, off);
    if (seg == 0) { e2f[v] = (float)s; e2d[v] = s; }
  } else {  // ---- pack_et body (proven), flattened grid ----
    if (!has_et) return;
    __shared__ float tile[64][65];
    const int idx = bx - 2304;
    const int vt = (idx & 63) * 64;
    const int kt = (idx >> 6) * 64;
    const int r = tid >> 4, c4 = (tid & 15) * 4;
#pragma unroll
    for (int i = 0; i < 4; ++i) {
      float4 v4 =
          *(const float4*)(E + (size_t)(vt + r + i * 16) * 256 + kt + c4);
      tile[r + i * 16][c4] = v4.x;
      tile[r + i * 16][c4 + 1] = v4.y;
      tile[r + i * 16][c4 + 2] = v4.z;
      tile[r + i * 16][c4 + 3] = v4.w;
    }
    __syncthreads();
#pragma unroll
    for (int i = 0; i < 4; ++i) {
      int kk = r + i * 16;
      float4 o;
      o.x = tile[c4 + 0][kk];
      o.y = tile[c4 + 1][kk];
      o.z = tile[c4 + 2][kk];
      o.w = tile[c4 + 3][kk];
      *(float4*)(ET + (size_t)(kt + kk) * 4096 + vt + c4) = o;
    }
  }
}

// ---- T1 main (proven): BM=64, chunk=256, BK=32, dbuf LDS ----
__global__ __launch_bounds__(256) void vq_main(
    const char* xpack, const char* __restrict__ epack,
    const float* __restrict__ e2f, const float* __restrict__ E,
    float* out, unsigned* __restrict__ cnt1, unsigned* __restrict__ list1) {
  extern __shared__ char smem[];
  const int tid = threadIdx.x;
  const int w = tid >> 6, lane = tid & 63;
  const int l15 = lane & 15, g = lane >> 4;
  const int rowbase = blockIdx.x * 64;

  // loader geometry (linear LDS dest, inverse-swizzled global source)
  const int rA = w * 16 + (lane >> 2);
  const int swz = (((lane & 3) ^ ((lane >> 2) & 3)) << 4);
  const char* aBase = xpack + (size_t)(rowbase + rA) * 1024 + swz;
  const char* bBase = epack + (size_t)(w * 64 + (lane >> 2)) * 512 + swz;
  const int ldA = w * 1024 + lane * 16;
  const int ldB = w * 4096 + lane * 16;

  // fragment read offsets (XOR-swizzled)
  const int fsw = ((g ^ (l15 & 3)) << 4);
  int aoff[4], boff[4];
#pragma unroll
  for (int mi = 0; mi < 4; ++mi) aoff[mi] = mi * 1024 + l15 * 64 + fsw;
#pragma unroll
  for (int ni = 0; ni < 4; ++ni) boff[ni] = w * 4096 + ni * 1024 + l15 * 64 + fsw;

  f32x4 acc[4][4];
#pragma unroll
  for (int mi = 0; mi < 4; ++mi)
#pragma unroll
    for (int ni = 0; ni < 4; ++ni) acc[mi][ni] = (f32x4){0.f, 0.f, 0.f, 0.f};

  float m1[16], m2[16];
  int i1[16];
#pragma unroll
  for (int s = 0; s < 16; ++s) { m1[s] = 3.4e38f; m2[s] = 3.4e38f; i1[s] = 0; }

#define STAGE(p, coff, koff)                                                \
  do {                                                                      \
    gl16(smem + (p)*4096 + ldA, aBase + (koff));                            \
    _Pragma("unroll") for (int i_ = 0; i_ < 4; ++i_)                        \
        gl16(smem + 8192 + (p)*16384 + ldB + i_ * 1024,                     \
             bBase + i_ * 8192 + (coff) + (koff));                          \
  } while (0)

  STAGE(0, (size_t)0, 0);
  __syncthreads();

#pragma unroll 1
  for (int c = 0; c < 16; ++c) {
    const size_t coff = (size_t)c * 131072;
#pragma unroll
    for (int k = 0; k < 8; ++k) {
      const int p = k & 1;
      if (!(c == 15 && k == 7)) {
        if (k == 7) STAGE(0, coff + 131072, 0);
        else STAGE(p ^ 1, coff, (k + 1) * 64);
      }
      const char* Ar = smem + p * 4096;
      const char* Br = smem + 8192 + p * 16384;
      f16x8 a[4], b[4];
#pragma unroll
      for (int mi = 0; mi < 4; ++mi) a[mi] = *(const f16x8*)(Ar + aoff[mi]);
#pragma unroll
      for (int ni = 0; ni < 4; ++ni) b[ni] = *(const f16x8*)(Br + boff[ni]);
#pragma unroll
      for (int mi = 0; mi < 4; ++mi)
#pragma unroll
        for (int ni = 0; ni < 4; ++ni)
          acc[mi][ni] = __builtin_amdgcn_mfma_f32_16x16x32_f16(
              a[mi], b[ni], acc[mi][ni], 0, 0, 0);
      __syncthreads();
    }
    // fused epilogue: distances + top-2, reset acc
    const int cb = c * 256 + w * 64;
#pragma unroll
    for (int ni = 0; ni < 4; ++ni) {
      const int col = cb + ni * 16 + l15;
      const float ev = e2f[col];
#pragma unroll
      for (int mi = 0; mi < 4; ++mi)
#pragma unroll
        for (int rg = 0; rg < 4; ++rg) {
          float d = fmaf(-2.0f, acc[mi][ni][rg], ev);
          const int s = mi * 4 + rg;
          bool better = d < m1[s];
          m2[s] = fminf(m2[s], better ? m1[s] : d);
          m1[s] = better ? d : m1[s];
          i1[s] = better ? col : i1[s];
          acc[mi][ni][rg] = 0.0f;
        }
    }
  }
#undef STAGE

  // butterfly merge across the 16 lanes sharing each row-set
#pragma unroll
  for (int s = 0; s < 16; ++s) {
#pragma unroll
    for (int off = 1; off < 16; off <<= 1) {
      float om1 = __shfl_xor(m1[s], off);
      float om2 = __shfl_xor(m2[s], off);
      int oi = __shfl_xor(i1[s], off);
      float nm2 = fminf(fminf(m2[s], om2), fmaxf(m1[s], om1));
      bool take = om1 < m1[s];
      m1[s] = take ? om1 : m1[s];
      i1[s] = take ? oi : i1[s];
      m2[s] = nm2;
    }
  }

  float* sm1 = (float*)smem;  // [4][64]
  float* sm2 = (float*)(smem + 1024);
  int* si1 = (int*)(smem + 2048);
  unsigned* swin = (unsigned*)(smem + 3072);
  __syncthreads();
  if (l15 == 0) {
#pragma unroll
    for (int s = 0; s < 16; ++s) {
      int r = (s >> 2) * 16 + g * 4 + (s & 3);
      sm1[w * 64 + r] = m1[s];
      sm2[w * 64 + r] = m2[s];
      si1[w * 64 + r] = i1[s];
    }
  }
  __syncthreads();
  if (tid < 64) {
    int r = tid;
    float am1 = sm1[r], am2 = sm2[r];
    int ai = si1[r];
#pragma unroll
    for (int ww = 1; ww < 4; ++ww) {
      float om1 = sm1[ww * 64 + r], om2 = sm2[ww * 64 + r];
      int oi = si1[ww * 64 + r];
      float nm2 = fminf(fminf(am2, om2), fmaxf(am1, om1));
      bool take = om1 < am1;
      am1 = take ? om1 : am1;
      ai = take ? oi : ai;
      am2 = nm2;
    }
    swin[r] = (unsigned)ai;
    if (am2 - am1 < TAU1) {
      unsigned p = atomicAdd(cnt1, 1u);
      if (p < LIST_CAP) list1[p] = (unsigned)(rowbase + r);
    }
  }
  __syncthreads();
  {
    int r = tid >> 2, part = tid & 3;
    unsigned wv = swin[r];
    const float4* src = (const float4*)(E + (size_t)wv * 256 + part * 64);
    float4* dst = (float4*)(out + (size_t)(rowbase + r) * 256 + part * 64);
#pragma unroll
    for (int q = 0; q < 16; ++q) dst[q] = src[q];
  }
}

// ---- T2 Stage A: per (8-row group, 1024-cw quarter) partial argmin ----
// 8 rows/group: each ET byte feeds 8 FMAs (halves redundant ET traffic).
__global__ __launch_bounds__(256) void vq_exact_part(
    const float* __restrict__ x, const float* __restrict__ ET,
    const double* __restrict__ e2d, Part* __restrict__ part,
    const unsigned* __restrict__ cnt1, const unsigned* __restrict__ list1) {
  __shared__ float xs[8][256];
  __shared__ double swd[32];
  __shared__ int swi[32];
  unsigned n = *cnt1;
  if (n > PROWS) n = PROWS;
  const unsigned nunits = ((n + 7) >> 3) << 2;  // 4 quarters per 8-row group
  const int tid = threadIdx.x;
  const int wid = tid >> 6, lane = tid & 63;
  for (unsigned u = blockIdx.x; u < nunits; u += gridDim.x) {
    const unsigned g = u >> 2;
    const int s = u & 3;
    const unsigned base = g * 8;
    __syncthreads();  // protect shared reuse across iterations
#pragma unroll
    for (int j = 0; j < 8; ++j) {
      unsigned jj = base + (unsigned)j;
      unsigned row = list1[jj < n ? jj : (n - 1)];
      xs[j][tid] = x[(size_t)row * 256 + tid];
    }
    __syncthreads();
    double best[8];
    int bi[8];
#pragma unroll
    for (int j = 0; j < 8; ++j) { best[j] = 1e300; bi[j] = 1 << 30; }
    {
      const int vb = s * 1024 + tid * 4;
      const char* ep = (const char*)(ET + vb);  // row stride 16384 B
      double a[8][4];
#pragma unroll
      for (int j = 0; j < 8; ++j)
#pragma unroll
        for (int c = 0; c < 4; ++c) a[j][c] = 0.0;
#pragma unroll 2
      for (int kb = 0; kb < 256; kb += 4) {
        float4 qf0 = *(const float4*)(ep + (size_t)(kb + 0) * 16384);
        float4 qf1 = *(const float4*)(ep + (size_t)(kb + 1) * 16384);
        float4 qf2 = *(const float4*)(ep + (size_t)(kb + 2) * 16384);
        float4 qf3 = *(const float4*)(ep + (size_t)(kb + 3) * 16384);
        double q0x = qf0.x, q0y = qf0.y, q0z = qf0.z, q0w = qf0.w;
        double q1x = qf1.x, q1y = qf1.y, q1z = qf1.z, q1w = qf1.w;
        double q2x = qf2.x, q2y = qf2.y, q2z = qf2.z, q2w = qf2.w;
        double q3x = qf3.x, q3y = qf3.y, q3z = qf3.z, q3w = qf3.w;
#pragma unroll
        for (int j = 0; j < 8; ++j) {
          float4 xv = *(const float4*)&xs[j][kb];  // broadcast b128 LDS read
          double x0 = xv.x, x1 = xv.y, x2 = xv.z, x3 = xv.w;
          a[j][0] += x0 * q0x + x1 * q1x + x2 * q2x + x3 * q3x;
          a[j][1] += x0 * q0y + x1 * q1y + x2 * q2y + x3 * q3y;
          a[j][2] += x0 * q0z + x1 * q1z + x2 * q2z + x3 * q3z;
          a[j][3] += x0 * q0w + x1 * q1w + x2 * q2w + x3 * q3w;
        }
      }
#pragma unroll
      for (int c = 0; c < 4; ++c) {
        double e2 = e2d[vb + c];
        int v = vb + c;
#pragma unroll
        for (int j = 0; j < 8; ++j) {
          double d = e2 - 2.0 * a[j][c];
          if (d < best[j] || (d == best[j] && v < bi[j])) {
            best[j] = d; bi[j] = v;
          }
        }
      }
    }
    // wave butterfly reduce per row, then cross-wave via LDS
#pragma unroll
    for (int j = 0; j < 8; ++j) {
#pragma unroll
      for (int off = 1; off < 64; off <<= 1) {
        double ob = __shfl_xor(best[j], off);
        int oi = __shfl_xor(bi[j], off);
        if (ob < best[j] || (ob == best[j] && oi < bi[j])) {
          best[j] = ob; bi[j] = oi;
        }
      }
      if (lane == 0) { swd[wid * 8 + j] = best[j]; swi[wid * 8 + j] = bi[j]; }
    }
    __syncthreads();
    if (tid < 8) {
      double b = swd[tid];
      int v = swi[tid];
#pragma unroll
      for (int ww = 1; ww < 4; ++ww) {
        double ob = swd[ww * 8 + tid];
        int oi = swi[ww * 8 + tid];
        if (ob < b || (ob == b && oi < v)) { b = ob; v = oi; }
      }
      unsigned i = base + (unsigned)tid;
      if (i < n) {
        Part pw;
        pw.d = b;
        pw.idx = (long long)v;
        part[(size_t)i * 4 + s] = pw;
      }
    }
  }
}

// ---- T2 Stage B + overflow: combine partials; slow-scan rows >= PROWS ----
__global__ __launch_bounds__(256) void vq_combine2(
    const Part* __restrict__ part, const float* __restrict__ x,
    const float* __restrict__ E, const double* __restrict__ e2d,
    const unsigned* __restrict__ cnt1, const unsigned* __restrict__ list1,
    float* __restrict__ out) {
  unsigned ntot = *cnt1;
  if (ntot > LIST_CAP) ntot = LIST_CAP;
  unsigned n = ntot > PROWS ? PROWS : ntot;
  const int tid = threadIdx.x;
  // phase 1: combine 4 partials per row, gather-write (proven body)
  {
    const int lr = tid >> 6, lane = tid & 63;
    for (unsigned i = blockIdx.x * 4u + (unsigned)lr; i < n;
         i += gridDim.x * 4u) {
      const Part* p = part + (size_t)i * 4;
      double b = p[0].d;
      long long v = p[0].idx;
#pragma unroll
      for (int s = 1; s < 4; ++s) {
        double ob = p[s].d;
        long long oi = p[s].idx;
        if (ob < b || (ob == b && oi < v)) { b = ob; v = oi; }
      }
      unsigned row = list1[i];
      float4 v4 = ((const float4*)(E + (size_t)v * 256))[lane];
      ((float4*)(out + (size_t)row * 256))[lane] = v4;
    }
  }
  // phase 2: overflow rows [PROWS, ntot) — full exact scan (normally no-op)
  if (ntot <= PROWS) return;
  __shared__ float4 xs[64];
  __shared__ double sd[256];
  __shared__ int si[256];
  for (unsigned i = PROWS + blockIdx.x; i < ntot; i += gridDim.x) {
    unsigned row = list1[i];
    __syncthreads();
    if (tid < 64) xs[tid] = ((const float4*)(x + (size_t)row * 256))[tid];
    __syncthreads();
    double best = 1e300;
    int bi = 1 << 30;
#pragma unroll 1
    for (int jg = 0; jg < 4; ++jg) {
      const int v0 = tid + jg * 1024;
      const float4* e0 = (const float4*)(E + (size_t)v0 * 256);
      const float4* e1 = (const float4*)(E + (size_t)(v0 + 256) * 256);
      const float4* e2 = (const float4*)(E + (size_t)(v0 + 512) * 256);
      const float4* e3 = (const float4*)(E + (size_t)(v0 + 768) * 256);
      double a0 = 0, a1 = 0, a2 = 0, a3 = 0;
      double b0 = 0, b1 = 0, b2 = 0, b3 = 0;
#pragma unroll 4
      for (int k4 = 0; k4 < 64; ++k4) {
        float4 xv = xs[k4];
        float4 q0 = e0[k4], q1 = e1[k4], q2 = e2[k4], q3 = e3[k4];
        a0 += (double)xv.x * q0.x + (double)xv.z * q0.z;
        b0 += (double)xv.y * q0.y + (double)xv.w * q0.w;
        a1 += (double)xv.x * q1.x + (double)xv.z * q1.z;
        b1 += (double)xv.y * q1.y + (double)xv.w * q1.w;
        a2 += (double)xv.x * q2.x + (double)xv.z * q2.z;
        b2 += (double)xv.y * q2.y + (double)xv.w * q2.w;
        a3 += (double)xv.x * q3.x + (double)xv.z * q3.z;
        b3 += (double)xv.y * q3.y + (double)xv.w * q3.w;
      }
      double d0 = e2d[v0] - 2.0 * (a0 + b0);
      double d1 = e2d[v0 + 256] - 2.0 * (a1 + b1);
      double d2 = e2d[v0 + 512] - 2.0 * (a2 + b2);
      double d3 = e2d[v0 + 768] - 2.0 * (a3 + b3);
      if (d0 < best || (d0 == best && v0 < bi)) { best = d0; bi = v0; }
      if (d1 < best || (d1 == best && v0 + 256 < bi)) { best = d1; bi = v0 + 256; }
      if (d2 < best || (d2 == best && v0 + 512 < bi)) { best = d2; bi = v0 + 512; }
      if (d3 < best || (d3 == best && v0 + 768 < bi)) { best = d3; bi = v0 + 768; }
    }
    sd[tid] = best;
    si[tid] = bi;
    __syncthreads();
    for (int s = 128; s > 0; s >>= 1) {
      if (tid < s) {
        double ob = sd[tid + s];
        int oi = si[tid + s];
        if (ob < sd[tid] || (ob == sd[tid] && oi < si[tid])) {
          sd[tid] = ob; si[tid] = oi;
        }
      }
      __syncthreads();
    }
    int win = si[0];
    if (tid < 64) {
      float4 v4 = ((const float4*)(E + (size_t)win * 256))[tid];
      ((float4*)(out + (size_t)row * 256))[tid] = v4;
    }
  }
}

// ---- T2 fallback for medium ws (proven): rows [start, n) direct from E ----
__global__ __launch_bounds__(256) void vq_exact_slow(
    const float* __restrict__ x, const float* __restrict__ E,
    const double* __restrict__ e2d, float* __restrict__ out,
    const unsigned* __restrict__ cnt1, const unsigned* __restrict__ list1,
    unsigned start) {
  __shared__ float4 xs[64];
  __shared__ double sd[256];
  __shared__ int si[256];
  unsigned n = *cnt1;
  if (n > LIST_CAP) n = LIST_CAP;
  const int tid = threadIdx.x;
  for (unsigned i = start + blockIdx.x; i < n; i += gridDim.x) {
    unsigned row = list1[i];
    __syncthreads();
    if (tid < 64) xs[tid] = ((const float4*)(x + (size_t)row * 256))[tid];
    __syncthreads();
    double best = 1e300;
    int bi = 1 << 30;
#pragma unroll 1
    for (int jg = 0; jg < 4; ++jg) {
      const int v0 = tid + jg * 1024;
      const float4* e0 = (const float4*)(E + (size_t)v0 * 256);
      const float4* e1 = (const float4*)(E + (size_t)(v0 + 256) * 256);
      const float4* e2 = (const float4*)(E + (size_t)(v0 + 512) * 256);
      const float4* e3 = (const float4*)(E + (size_t)(v0 + 768) * 256);
      double a0 = 0, a1 = 0, a2 = 0, a3 = 0;
      double b0 = 0, b1 = 0, b2 = 0, b3 = 0;
#pragma unroll 4
      for (int k4 = 0; k4 < 64; ++k4) {
        float4 xv = xs[k4];
        float4 q0 = e0[k4], q1 = e1[k4], q2 = e2[k4], q3 = e3[k4];
        a0 += (double)xv.x * q0.x + (double)xv.z * q0.z;
        b0 += (double)xv.y * q0.y + (double)xv.w * q0.w;
        a1 += (double)xv.x * q1.x + (double)xv.z * q1.z;
        b1 += (double)xv.y * q1.y + (double)xv.w * q1.w;
        a2 += (double)xv.x * q2.x + (double)xv.z * q2.z;
        b2 += (double)xv.y * q2.y + (double)xv.w * q2.w;
        a3 += (double)xv.x * q3.x + (double)xv.z * q3.z;
        b3 += (double)xv.y * q3.y + (double)xv.w * q3.w;
      }
      double d0 = e2d[v0] - 2.0 * (a0 + b0);
      double d1 = e2d[v0 + 256] - 2.0 * (a1 + b1);
      double d2 = e2d[v0 + 512] - 2.0 * (a2 + b2);
      double d3 = e2d[v0 + 768] - 2.0 * (a3 + b3);
      if (d0 < best || (d0 == best && v0 < bi)) { best = d0; bi = v0; }
      if (d1 < best || (d1 == best && v0 + 256 < bi)) { best = d1; bi = v0 + 256; }
      if (d2 < best || (d2 == best && v0 + 512 < bi)) { best = d2; bi = v0 + 512; }
      if (d3 < best || (d3 == best && v0 + 768 < bi)) { best = d3; bi = v0 + 768; }
    }
    sd[tid] = best;
    si[tid] = bi;
    __syncthreads();
    for (int s = 128; s > 0; s >>= 1) {
      if (tid < s) {
        double ob = sd[tid + s];
        int oi = si[tid + s];
        if (ob < sd[tid] || (ob == sd[tid] && oi < si[tid])) {
          sd[tid] = ob; si[tid] = oi;
        }
      }
      __syncthreads();
    }
    int win = si[0];
    if (tid < 64) {
      float4 v4 = ((const float4*)(E + (size_t)win * 256))[tid];
      ((float4*)(out + (size_t)row * 256))[tid] = v4;
    }
  }
}

// ---- insurance: exact fp64 scan of ALL rows (only if ws too small) ----
__global__ void scan_all(const float* __restrict__ x,
                         const float* __restrict__ E, float* out) {
  __shared__ double sd[256];
  __shared__ int si[256];
  for (int row = blockIdx.x; row < 32768; row += gridDim.x) {
    const float* xr = x + (size_t)row * 256;
    double best = 1e300;
    int bi = 1 << 30;
    for (int v = threadIdx.x; v < 4096; v += 256) {
      const float* ev = E + (size_t)v * 256;
      double a0 = 0, a1 = 0, a2 = 0, a3 = 0;
      for (int k = 0; k < 256; k += 4) {
        double d0 = (double)xr[k] - (double)ev[k];
        double d1 = (double)xr[k + 1] - (double)ev[k + 1];
        double d2 = (double)xr[k + 2] - (double)ev[k + 2];
        double d3 = (double)xr[k + 3] - (double)ev[k + 3];
        a0 += d0 * d0; a1 += d1 * d1; a2 += d2 * d2; a3 += d3 * d3;
      }
      double d = (a0 + a1) + (a2 + a3);
      if (d < best || (d == best && v < bi)) { best = d; bi = v; }
    }
    sd[threadIdx.x] = best; si[threadIdx.x] = bi;
    __syncthreads();
    for (int s = 128; s > 0; s >>= 1) {
      if ((int)threadIdx.x < s) {
        double ob = sd[threadIdx.x + s];
        int oi = si[threadIdx.x + s];
        if (ob < sd[threadIdx.x] ||
            (ob == sd[threadIdx.x] && oi < si[threadIdx.x])) {
          sd[threadIdx.x] = ob; si[threadIdx.x] = oi;
        }
      }
      __syncthreads();
    }
    int win = si[0];
    __syncthreads();
    out[(size_t)row * 256 + threadIdx.x] = E[(size_t)win * 256 + threadIdx.x];
  }
}

extern "C" void kernel_launch(void* const* d_in, const int* in_sizes, int n_in,
                              void* d_out, int out_size, void* d_ws,
                              size_t ws_size, hipStream_t stream) {
  (void)in_sizes; (void)n_in; (void)out_size;
  const float* x = (const float*)d_in[0];
  const float* E = (const float*)d_in[1];
  float* out = (float*)d_out;
  char* ws = (char*)d_ws;
  // ws: [cnt 64][e2f 16K][e2d 32K][ehi 2M][list1 256K][ET 4M][part 256K][xpack 32M?]
  const size_t XOFF = 64 + 16384 + 32768 + 2097152 + 262144;  // 2408512
  const size_t ET_OFF = XOFF;
  const size_t PART_OFF = ET_OFF + 4194304;
  const size_t NEED_ET = PART_OFF + (size_t)PROWS * 4 * sizeof(Part);  // +256K
  const size_t NEED_BIG = NEED_ET + 33554432;
  if (ws_size < XOFF) {
    scan_all<<<2048, 256, 0, stream>>>(x, E, out);
    return;
  }
  unsigned* cnt1 = (unsigned*)ws;
  float* e2f = (float*)(ws + 64);
  double* e2d = (double*)(ws + 64 + 16384);
  char* ehi = ws + 64 + 16384 + 32768;
  unsigned* list1 = (unsigned*)(ehi + 2097152);
  char* xpack = (ws_size >= NEED_BIG) ? (ws + NEED_ET) : (char*)d_out;

  if (ws_size >= NEED_ET) {
    float* ETp = (float*)(ws + ET_OFF);
    Part* partp = (Part*)(ws + PART_OFF);
    fused_pack<<<2560, 256, 0, stream>>>(x, xpack, E, ehi, e2f, e2d, ETp, 1,
                                         cnt1);
    vq_main<<<512, 256, 40960, stream>>>(xpack, ehi, e2f, E, out, cnt1, list1);
    vq_exact_part<<<512, 256, 0, stream>>>(x, ETp, e2d, partp, cnt1, list1);
    vq_combine2<<<256, 256, 0, stream>>>(partp, x, E, e2d, cnt1, list1, out);
  } else {
    fused_pack<<<2560, 256, 0, stream>>>(x, xpack, E, ehi, e2f, e2d, nullptr,
                                         0, cnt1);
    vq_main<<<512, 256, 40960, stream>>>(xpack, ehi, e2f, E, out, cnt1, list1);
    vq_exact_slow<<<1024, 256, 0, stream>>>(x, E, e2d, out, cnt1, list1, 0u);
  }
}

// Round 18
// 192.816 us; speedup vs baseline: 1.0847x; 1.0847x over previous
//
#include <hip/hip_runtime.h>

// VQ nearest-codeword, 2-tier (round-16 configuration — session best, 192.8us):
//  fused_pack: memset(cnt) + pack_x + pack_e + pack_et in ONE dispatch.
//  T1 vq_main: fp16 single-pass MFMA GEMM, fused per-row top-2 (proven).
//  T2: vq_exact_part (ET-coalesced partial argmin, 4-row group, kb unroll 4)
//      + vq_combine2 (combine partials + overflow scan).

typedef float f32x4 __attribute__((ext_vector_type(4)));
typedef _Float16 f16x8 __attribute__((ext_vector_type(8)));

#define TAU1 0.15f
#define LIST_CAP 65536u
#define PROWS 4096u

struct Part { double d; long long idx; };  // 16 B

__device__ __forceinline__ unsigned short f16b(float f) {
  _Float16 h = (_Float16)f;
  return __builtin_bit_cast(unsigned short, h);
}

__device__ __forceinline__ void gl16(char* lds, const char* g) {
  __builtin_amdgcn_global_load_lds(
      (const __attribute__((address_space(1))) void*)g,
      (__attribute__((address_space(3))) void*)lds, 16, 0, 0);
}

// ---- fused pack: blocks [0,2048) pack_x, [2048,2304) pack_e (+cnt zero),
//      [2304,2560) pack_et (skipped when has_et==0) ----
__global__ __launch_bounds__(256) void fused_pack(
    const float* __restrict__ x, char* xp, const float* __restrict__ E,
    char* __restrict__ ehi, float* __restrict__ e2f, double* __restrict__ e2d,
    float* __restrict__ ET, int has_et, unsigned* __restrict__ cnt1) {
  const int bx = blockIdx.x;
  const int tid = threadIdx.x;
  if (bx < 2048) {  // ---- pack_x body (proven) ----
    int gid = bx * 256 + tid;
    int row = gid >> 4, seg = gid & 15;
    const float4* xr = (const float4*)(x + (size_t)row * 256 + seg * 16);
    unsigned o[8];
#pragma unroll
    for (int q = 0; q < 4; ++q) {
      float4 f = xr[q];
      o[q * 2]     = (unsigned)f16b(f.x) | ((unsigned)f16b(f.y) << 16);
      o[q * 2 + 1] = (unsigned)f16b(f.z) | ((unsigned)f16b(f.w) << 16);
    }
    uint4* dst = (uint4*)(xp + (size_t)row * 1024 + seg * 32);
    dst[0] = make_uint4(o[0], o[1], o[2], o[3]);
    dst[1] = make_uint4(o[4], o[5], o[6], o[7]);
  } else if (bx < 2304) {  // ---- pack_e body (proven) + cnt zero ----
    if (bx == 2048 && tid == 0) *cnt1 = 0u;
    int vl = tid >> 4, seg = tid & 15;
    int v = (bx - 2048) * 16 + vl;
    const float4* er = (const float4*)(E + (size_t)v * 256 + seg * 16);
    unsigned oh[8];
    double s = 0.0;
#pragma unroll
    for (int q = 0; q < 4; ++q) {
      float4 f = er[q];
      float vf[4] = {f.x, f.y, f.z, f.w};
      unsigned short hb[4];
#pragma unroll
      for (int e = 0; e < 4; ++e) {
        float fv = vf[e];
        s += (double)fv * (double)fv;
        hb[e] = f16b(fv);
      }
      oh[q * 2]     = (unsigned)hb[0] | ((unsigned)hb[1] << 16);
      oh[q * 2 + 1] = (unsigned)hb[2] | ((unsigned)hb[3] << 16);
    }
    uint4* dh = (uint4*)(ehi + (size_t)v * 512 + seg * 32);
    dh[0] = make_uint4(oh[0], oh[1], oh[2], oh[3]);
    dh[1] = make_uint4(oh[4], oh[5], oh[6], oh[7]);
#pragma unroll
    for (int off = 1; off < 16; off <<= 1) s += __shfl_xor(s, off);
    if (seg == 0) { e2f[v] = (float)s; e2d[v] = s; }
  } else {  // ---- pack_et body (proven), flattened grid ----
    if (!has_et) return;
    __shared__ float tile[64][65];
    const int idx = bx - 2304;
    const int vt = (idx & 63) * 64;
    const int kt = (idx >> 6) * 64;
    const int r = tid >> 4, c4 = (tid & 15) * 4;
#pragma unroll
    for (int i = 0; i < 4; ++i) {
      float4 v4 =
          *(const float4*)(E + (size_t)(vt + r + i * 16) * 256 + kt + c4);
      tile[r + i * 16][c4] = v4.x;
      tile[r + i * 16][c4 + 1] = v4.y;
      tile[r + i * 16][c4 + 2] = v4.z;
      tile[r + i * 16][c4 + 3] = v4.w;
    }
    __syncthreads();
#pragma unroll
    for (int i = 0; i < 4; ++i) {
      int kk = r + i * 16;
      float4 o;
      o.x = tile[c4 + 0][kk];
      o.y = tile[c4 + 1][kk];
      o.z = tile[c4 + 2][kk];
      o.w = tile[c4 + 3][kk];
      *(float4*)(ET + (size_t)(kt + kk) * 4096 + vt + c4) = o;
    }
  }
}

// ---- T1 main (proven): BM=64, chunk=256, BK=32, dbuf LDS ----
__global__ __launch_bounds__(256) void vq_main(
    const char* xpack, const char* __restrict__ epack,
    const float* __restrict__ e2f, const float* __restrict__ E,
    float* out, unsigned* __restrict__ cnt1, unsigned* __restrict__ list1) {
  extern __shared__ char smem[];
  const int tid = threadIdx.x;
  const int w = tid >> 6, lane = tid & 63;
  const int l15 = lane & 15, g = lane >> 4;
  const int rowbase = blockIdx.x * 64;

  // loader geometry (linear LDS dest, inverse-swizzled global source)
  const int rA = w * 16 + (lane >> 2);
  const int swz = (((lane & 3) ^ ((lane >> 2) & 3)) << 4);
  const char* aBase = xpack + (size_t)(rowbase + rA) * 1024 + swz;
  const char* bBase = epack + (size_t)(w * 64 + (lane >> 2)) * 512 + swz;
  const int ldA = w * 1024 + lane * 16;
  const int ldB = w * 4096 + lane * 16;

  // fragment read offsets (XOR-swizzled)
  const int fsw = ((g ^ (l15 & 3)) << 4);
  int aoff[4], boff[4];
#pragma unroll
  for (int mi = 0; mi < 4; ++mi) aoff[mi] = mi * 1024 + l15 * 64 + fsw;
#pragma unroll
  for (int ni = 0; ni < 4; ++ni) boff[ni] = w * 4096 + ni * 1024 + l15 * 64 + fsw;

  f32x4 acc[4][4];
#pragma unroll
  for (int mi = 0; mi < 4; ++mi)
#pragma unroll
    for (int ni = 0; ni < 4; ++ni) acc[mi][ni] = (f32x4){0.f, 0.f, 0.f, 0.f};

  float m1[16], m2[16];
  int i1[16];
#pragma unroll
  for (int s = 0; s < 16; ++s) { m1[s] = 3.4e38f; m2[s] = 3.4e38f; i1[s] = 0; }

#define STAGE(p, coff, koff)                                                \
  do {                                                                      \
    gl16(smem + (p)*4096 + ldA, aBase + (koff));                            \
    _Pragma("unroll") for (int i_ = 0; i_ < 4; ++i_)                        \
        gl16(smem + 8192 + (p)*16384 + ldB + i_ * 1024,                     \
             bBase + i_ * 8192 + (coff) + (koff));                          \
  } while (0)

  STAGE(0, (size_t)0, 0);
  __syncthreads();

#pragma unroll 1
  for (int c = 0; c < 16; ++c) {
    const size_t coff = (size_t)c * 131072;
#pragma unroll
    for (int k = 0; k < 8; ++k) {
      const int p = k & 1;
      if (!(c == 15 && k == 7)) {
        if (k == 7) STAGE(0, coff + 131072, 0);
        else STAGE(p ^ 1, coff, (k + 1) * 64);
      }
      const char* Ar = smem + p * 4096;
      const char* Br = smem + 8192 + p * 16384;
      f16x8 a[4], b[4];
#pragma unroll
      for (int mi = 0; mi < 4; ++mi) a[mi] = *(const f16x8*)(Ar + aoff[mi]);
#pragma unroll
      for (int ni = 0; ni < 4; ++ni) b[ni] = *(const f16x8*)(Br + boff[ni]);
#pragma unroll
      for (int mi = 0; mi < 4; ++mi)
#pragma unroll
        for (int ni = 0; ni < 4; ++ni)
          acc[mi][ni] = __builtin_amdgcn_mfma_f32_16x16x32_f16(
              a[mi], b[ni], acc[mi][ni], 0, 0, 0);
      __syncthreads();
    }
    // fused epilogue: distances + top-2, reset acc
    const int cb = c * 256 + w * 64;
#pragma unroll
    for (int ni = 0; ni < 4; ++ni) {
      const int col = cb + ni * 16 + l15;
      const float ev = e2f[col];
#pragma unroll
      for (int mi = 0; mi < 4; ++mi)
#pragma unroll
        for (int rg = 0; rg < 4; ++rg) {
          float d = fmaf(-2.0f, acc[mi][ni][rg], ev);
          const int s = mi * 4 + rg;
          bool better = d < m1[s];
          m2[s] = fminf(m2[s], better ? m1[s] : d);
          m1[s] = better ? d : m1[s];
          i1[s] = better ? col : i1[s];
          acc[mi][ni][rg] = 0.0f;
        }
    }
  }
#undef STAGE

  // butterfly merge across the 16 lanes sharing each row-set
#pragma unroll
  for (int s = 0; s < 16; ++s) {
#pragma unroll
    for (int off = 1; off < 16; off <<= 1) {
      float om1 = __shfl_xor(m1[s], off);
      float om2 = __shfl_xor(m2[s], off);
      int oi = __shfl_xor(i1[s], off);
      float nm2 = fminf(fminf(m2[s], om2), fmaxf(m1[s], om1));
      bool take = om1 < m1[s];
      m1[s] = take ? om1 : m1[s];
      i1[s] = take ? oi : i1[s];
      m2[s] = nm2;
    }
  }

  float* sm1 = (float*)smem;  // [4][64]
  float* sm2 = (float*)(smem + 1024);
  int* si1 = (int*)(smem + 2048);
  unsigned* swin = (unsigned*)(smem + 3072);
  __syncthreads();
  if (l15 == 0) {
#pragma unroll
    for (int s = 0; s < 16; ++s) {
      int r = (s >> 2) * 16 + g * 4 + (s & 3);
      sm1[w * 64 + r] = m1[s];
      sm2[w * 64 + r] = m2[s];
      si1[w * 64 + r] = i1[s];
    }
  }
  __syncthreads();
  if (tid < 64) {
    int r = tid;
    float am1 = sm1[r], am2 = sm2[r];
    int ai = si1[r];
#pragma unroll
    for (int ww = 1; ww < 4; ++ww) {
      float om1 = sm1[ww * 64 + r], om2 = sm2[ww * 64 + r];
      int oi = si1[ww * 64 + r];
      float nm2 = fminf(fminf(am2, om2), fmaxf(am1, om1));
      bool take = om1 < am1;
      am1 = take ? om1 : am1;
      ai = take ? oi : ai;
      am2 = nm2;
    }
    swin[r] = (unsigned)ai;
    if (am2 - am1 < TAU1) {
      unsigned p = atomicAdd(cnt1, 1u);
      if (p < LIST_CAP) list1[p] = (unsigned)(rowbase + r);
    }
  }
  __syncthreads();
  {
    int r = tid >> 2, part = tid & 3;
    unsigned wv = swin[r];
    const float4* src = (const float4*)(E + (size_t)wv * 256 + part * 64);
    float4* dst = (float4*)(out + (size_t)(rowbase + r) * 256 + part * 64);
#pragma unroll
    for (int q = 0; q < 16; ++q) dst[q] = src[q];
  }
}

// ---- T2 Stage A: per (4-row group, 1024-cw quarter) partial argmin ----
// kb-loop unroll 4: 16 independent 16B L2 loads in flight (latency hiding).
__global__ __launch_bounds__(256) void vq_exact_part(
    const float* __restrict__ x, const float* __restrict__ ET,
    const double* __restrict__ e2d, Part* __restrict__ part,
    const unsigned* __restrict__ cnt1, const unsigned* __restrict__ list1) {
  __shared__ float xs[4][256];
  __shared__ double swd[16];
  __shared__ int swi[16];
  unsigned n = *cnt1;
  if (n > PROWS) n = PROWS;
  const unsigned nunits = ((n + 3) >> 2) << 2;  // 4 splits per group
  const int tid = threadIdx.x;
  const int wid = tid >> 6, lane = tid & 63;
  for (unsigned u = blockIdx.x; u < nunits; u += gridDim.x) {
    const unsigned g = u >> 2;
    const int s = u & 3;
    const unsigned base = g * 4;
    __syncthreads();  // protect shared reuse across iterations
#pragma unroll
    for (int j = 0; j < 4; ++j) {
      unsigned jj = base + (unsigned)j;
      unsigned row = list1[jj < n ? jj : (n - 1)];
      xs[j][tid] = x[(size_t)row * 256 + tid];
    }
    __syncthreads();
    double best[4];
    int bi[4];
#pragma unroll
    for (int j = 0; j < 4; ++j) { best[j] = 1e300; bi[j] = 1 << 30; }
    {
      const int vb = s * 1024 + tid * 4;
      const char* ep = (const char*)(ET + vb);  // row stride 16384 B
      double a[4][4];
#pragma unroll
      for (int j = 0; j < 4; ++j)
#pragma unroll
        for (int c = 0; c < 4; ++c) a[j][c] = 0.0;
#pragma unroll 4
      for (int kb = 0; kb < 256; kb += 4) {
        float4 qf0 = *(const float4*)(ep + (size_t)(kb + 0) * 16384);
        float4 qf1 = *(const float4*)(ep + (size_t)(kb + 1) * 16384);
        float4 qf2 = *(const float4*)(ep + (size_t)(kb + 2) * 16384);
        float4 qf3 = *(const float4*)(ep + (size_t)(kb + 3) * 16384);
        double q0x = qf0.x, q0y = qf0.y, q0z = qf0.z, q0w = qf0.w;
        double q1x = qf1.x, q1y = qf1.y, q1z = qf1.z, q1w = qf1.w;
        double q2x = qf2.x, q2y = qf2.y, q2z = qf2.z, q2w = qf2.w;
        double q3x = qf3.x, q3y = qf3.y, q3z = qf3.z, q3w = qf3.w;
#pragma unroll
        for (int j = 0; j < 4; ++j) {
          float4 xv = *(const float4*)&xs[j][kb];  // broadcast b128 LDS read
          double x0 = xv.x, x1 = xv.y, x2 = xv.z, x3 = xv.w;
          a[j][0] += x0 * q0x + x1 * q1x + x2 * q2x + x3 * q3x;
          a[j][1] += x0 * q0y + x1 * q1y + x2 * q2y + x3 * q3y;
          a[j][2] += x0 * q0z + x1 * q1z + x2 * q2z + x3 * q3z;
          a[j][3] += x0 * q0w + x1 * q1w + x2 * q2w + x3 * q3w;
        }
      }
#pragma unroll
      for (int c = 0; c < 4; ++c) {
        double e2 = e2d[vb + c];
        int v = vb + c;
#pragma unroll
        for (int j = 0; j < 4; ++j) {
          double d = e2 - 2.0 * a[j][c];
          if (d < best[j] || (d == best[j] && v < bi[j])) {
            best[j] = d; bi[j] = v;
          }
        }
      }
    }
    // wave butterfly reduce per row, then cross-wave via LDS
#pragma unroll
    for (int j = 0; j < 4; ++j) {
#pragma unroll
      for (int off = 1; off < 64; off <<= 1) {
        double ob = __shfl_xor(best[j], off);
        int oi = __shfl_xor(bi[j], off);
        if (ob < best[j] || (ob == best[j] && oi < bi[j])) {
          best[j] = ob; bi[j] = oi;
        }
      }
      if (lane == 0) { swd[wid * 4 + j] = best[j]; swi[wid * 4 + j] = bi[j]; }
    }
    __syncthreads();
    if (tid < 4) {
      double b = swd[tid];
      int v = swi[tid];
#pragma unroll
      for (int ww = 1; ww < 4; ++ww) {
        double ob = swd[ww * 4 + tid];
        int oi = swi[ww * 4 + tid];
        if (ob < b || (ob == b && oi < v)) { b = ob; v = oi; }
      }
      unsigned i = base + (unsigned)tid;
      if (i < n) {
        Part pw;
        pw.d = b;
        pw.idx = (long long)v;
        part[(size_t)i * 4 + s] = pw;
      }
    }
  }
}

// ---- T2 Stage B + overflow: combine partials; slow-scan rows >= PROWS ----
__global__ __launch_bounds__(256) void vq_combine2(
    const Part* __restrict__ part, const float* __restrict__ x,
    const float* __restrict__ E, const double* __restrict__ e2d,
    const unsigned* __restrict__ cnt1, const unsigned* __restrict__ list1,
    float* __restrict__ out) {
  unsigned ntot = *cnt1;
  if (ntot > LIST_CAP) ntot = LIST_CAP;
  unsigned n = ntot > PROWS ? PROWS : ntot;
  const int tid = threadIdx.x;
  // phase 1: combine 4 partials per row, gather-write (proven body)
  {
    const int lr = tid >> 6, lane = tid & 63;
    for (unsigned i = blockIdx.x * 4u + (unsigned)lr; i < n;
         i += gridDim.x * 4u) {
      const Part* p = part + (size_t)i * 4;
      double b = p[0].d;
      long long v = p[0].idx;
#pragma unroll
      for (int s = 1; s < 4; ++s) {
        double ob = p[s].d;
        long long oi = p[s].idx;
        if (ob < b || (ob == b && oi < v)) { b = ob; v = oi; }
      }
      unsigned row = list1[i];
      float4 v4 = ((const float4*)(E + (size_t)v * 256))[lane];
      ((float4*)(out + (size_t)row * 256))[lane] = v4;
    }
  }
  // phase 2: overflow rows [PROWS, ntot) — full exact scan (normally no-op)
  if (ntot <= PROWS) return;
  __shared__ float4 xs[64];
  __shared__ double sd[256];
  __shared__ int si[256];
  for (unsigned i = PROWS + blockIdx.x; i < ntot; i += gridDim.x) {
    unsigned row = list1[i];
    __syncthreads();
    if (tid < 64) xs[tid] = ((const float4*)(x + (size_t)row * 256))[tid];
    __syncthreads();
    double best = 1e300;
    int bi = 1 << 30;
#pragma unroll 1
    for (int jg = 0; jg < 4; ++jg) {
      const int v0 = tid + jg * 1024;
      const float4* e0 = (const float4*)(E + (size_t)v0 * 256);
      const float4* e1 = (const float4*)(E + (size_t)(v0 + 256) * 256);
      const float4* e2 = (const float4*)(E + (size_t)(v0 + 512) * 256);
      const float4* e3 = (const float4*)(E + (size_t)(v0 + 768) * 256);
      double a0 = 0, a1 = 0, a2 = 0, a3 = 0;
      double b0 = 0, b1 = 0, b2 = 0, b3 = 0;
#pragma unroll 4
      for (int k4 = 0; k4 < 64; ++k4) {
        float4 xv = xs[k4];
        float4 q0 = e0[k4], q1 = e1[k4], q2 = e2[k4], q3 = e3[k4];
        a0 += (double)xv.x * q0.x + (double)xv.z * q0.z;
        b0 += (double)xv.y * q0.y + (double)xv.w * q0.w;
        a1 += (double)xv.x * q1.x + (double)xv.z * q1.z;
        b1 += (double)xv.y * q1.y + (double)xv.w * q1.w;
        a2 += (double)xv.x * q2.x + (double)xv.z * q2.z;
        b2 += (double)xv.y * q2.y + (double)xv.w * q2.w;
        a3 += (double)xv.x * q3.x + (double)xv.z * q3.z;
        b3 += (double)xv.y * q3.y + (double)xv.w * q3.w;
      }
      double d0 = e2d[v0] - 2.0 * (a0 + b0);
      double d1 = e2d[v0 + 256] - 2.0 * (a1 + b1);
      double d2 = e2d[v0 + 512] - 2.0 * (a2 + b2);
      double d3 = e2d[v0 + 768] - 2.0 * (a3 + b3);
      if (d0 < best || (d0 == best && v0 < bi)) { best = d0; bi = v0; }
      if (d1 < best || (d1 == best && v0 + 256 < bi)) { best = d1; bi = v0 + 256; }
      if (d2 < best || (d2 == best && v0 + 512 < bi)) { best = d2; bi = v0 + 512; }
      if (d3 < best || (d3 == best && v0 + 768 < bi)) { best = d3; bi = v0 + 768; }
    }
    sd[tid] = best;
    si[tid] = bi;
    __syncthreads();
    for (int s = 128; s > 0; s >>= 1) {
      if (tid < s) {
        double ob = sd[tid + s];
        int oi = si[tid + s];
        if (ob < sd[tid] || (ob == sd[tid] && oi < si[tid])) {
          sd[tid] = ob; si[tid] = oi;
        }
      }
      __syncthreads();
    }
    int win = si[0];
    if (tid < 64) {
      float4 v4 = ((const float4*)(E + (size_t)win * 256))[tid];
      ((float4*)(out + (size_t)row * 256))[tid] = v4;
    }
  }
}

// ---- T2 fallback for medium ws (proven): rows [start, n) direct from E ----
__global__ __launch_bounds__(256) void vq_exact_slow(
    const float* __restrict__ x, const float* __restrict__ E,
    const double* __restrict__ e2d, float* __restrict__ out,
    const unsigned* __restrict__ cnt1, const unsigned* __restrict__ list1,
    unsigned start) {
  __shared__ float4 xs[64];
  __shared__ double sd[256];
  __shared__ int si[256];
  unsigned n = *cnt1;
  if (n > LIST_CAP) n = LIST_CAP;
  const int tid = threadIdx.x;
  for (unsigned i = start + blockIdx.x; i < n; i += gridDim.x) {
    unsigned row = list1[i];
    __syncthreads();
    if (tid < 64) xs[tid] = ((const float4*)(x + (size_t)row * 256))[tid];
    __syncthreads();
    double best = 1e300;
    int bi = 1 << 30;
#pragma unroll 1
    for (int jg = 0; jg < 4; ++jg) {
      const int v0 = tid + jg * 1024;
      const float4* e0 = (const float4*)(E + (size_t)v0 * 256);
      const float4* e1 = (const float4*)(E + (size_t)(v0 + 256) * 256);
      const float4* e2 = (const float4*)(E + (size_t)(v0 + 512) * 256);
      const float4* e3 = (const float4*)(E + (size_t)(v0 + 768) * 256);
      double a0 = 0, a1 = 0, a2 = 0, a3 = 0;
      double b0 = 0, b1 = 0, b2 = 0, b3 = 0;
#pragma unroll 4
      for (int k4 = 0; k4 < 64; ++k4) {
        float4 xv = xs[k4];
        float4 q0 = e0[k4], q1 = e1[k4], q2 = e2[k4], q3 = e3[k4];
        a0 += (double)xv.x * q0.x + (double)xv.z * q0.z;
        b0 += (double)xv.y * q0.y + (double)xv.w * q0.w;
        a1 += (double)xv.x * q1.x + (double)xv.z * q1.z;
        b1 += (double)xv.y * q1.y + (double)xv.w * q1.w;
        a2 += (double)xv.x * q2.x + (double)xv.z * q2.z;
        b2 += (double)xv.y * q2.y + (double)xv.w * q2.w;
        a3 += (double)xv.x * q3.x + (double)xv.z * q3.z;
        b3 += (double)xv.y * q3.y + (double)xv.w * q3.w;
      }
      double d0 = e2d[v0] - 2.0 * (a0 + b0);
      double d1 = e2d[v0 + 256] - 2.0 * (a1 + b1);
      double d2 = e2d[v0 + 512] - 2.0 * (a2 + b2);
      double d3 = e2d[v0 + 768] - 2.0 * (a3 + b3);
      if (d0 < best || (d0 == best && v0 < bi)) { best = d0; bi = v0; }
      if (d1 < best || (d1 == best && v0 + 256 < bi)) { best = d1; bi = v0 + 256; }
      if (d2 < best || (d2 == best && v0 + 512 < bi)) { best = d2; bi = v0 + 512; }
      if (d3 < best || (d3 == best && v0 + 768 < bi)) { best = d3; bi = v0 + 768; }
    }
    sd[tid] = best;
    si[tid] = bi;
    __syncthreads();
    for (int s = 128; s > 0; s >>= 1) {
      if (tid < s) {
        double ob = sd[tid + s];
        int oi = si[tid + s];
        if (ob < sd[tid] || (ob == sd[tid] && oi < si[tid])) {
          sd[tid] = ob; si[tid] = oi;
        }
      }
      __syncthreads();
    }
    int win = si[0];
    if (tid < 64) {
      float4 v4 = ((const float4*)(E + (size_t)win * 256))[tid];
      ((float4*)(out + (size_t)row * 256))[tid] = v4;
    }
  }
}

// ---- insurance: exact fp64 scan of ALL rows (only if ws too small) ----
__global__ void scan_all(const float* __restrict__ x,
                         const float* __restrict__ E, float* out) {
  __shared__ double sd[256];
  __shared__ int si[256];
  for (int row = blockIdx.x; row < 32768; row += gridDim.x) {
    const float* xr = x + (size_t)row * 256;
    double best = 1e300;
    int bi = 1 << 30;
    for (int v = threadIdx.x; v < 4096; v += 256) {
      const float* ev = E + (size_t)v * 256;
      double a0 = 0, a1 = 0, a2 = 0, a3 = 0;
      for (int k = 0; k < 256; k += 4) {
        double d0 = (double)xr[k] - (double)ev[k];
        double d1 = (double)xr[k + 1] - (double)ev[k + 1];
        double d2 = (double)xr[k + 2] - (double)ev[k + 2];
        double d3 = (double)xr[k + 3] - (double)ev[k + 3];
        a0 += d0 * d0; a1 += d1 * d1; a2 += d2 * d2; a3 += d3 * d3;
      }
      double d = (a0 + a1) + (a2 + a3);
      if (d < best || (d == best && v < bi)) { best = d; bi = v; }
    }
    sd[threadIdx.x] = best; si[threadIdx.x] = bi;
    __syncthreads();
    for (int s = 128; s > 0; s >>= 1) {
      if ((int)threadIdx.x < s) {
        double ob = sd[threadIdx.x + s];
        int oi = si[threadIdx.x + s];
        if (ob < sd[threadIdx.x] ||
            (ob == sd[threadIdx.x] && oi < si[threadIdx.x])) {
          sd[threadIdx.x] = ob; si[threadIdx.x] = oi;
        }
      }
      __syncthreads();
    }
    int win = si[0];
    __syncthreads();
    out[(size_t)row * 256 + threadIdx.x] = E[(size_t)win * 256 + threadIdx.x];
  }
}

extern "C" void kernel_launch(void* const* d_in, const int* in_sizes, int n_in,
                              void* d_out, int out_size, void* d_ws,
                              size_t ws_size, hipStream_t stream) {
  (void)in_sizes; (void)n_in; (void)out_size;
  const float* x = (const float*)d_in[0];
  const float* E = (const float*)d_in[1];
  float* out = (float*)d_out;
  char* ws = (char*)d_ws;
  // ws: [cnt 64][e2f 16K][e2d 32K][ehi 2M][list1 256K][ET 4M][part 256K][xpack 32M?]
  const size_t XOFF = 64 + 16384 + 32768 + 2097152 + 262144;  // 2408512
  const size_t ET_OFF = XOFF;
  const size_t PART_OFF = ET_OFF + 4194304;
  const size_t NEED_ET = PART_OFF + (size_t)PROWS * 4 * sizeof(Part);  // +256K
  const size_t NEED_BIG = NEED_ET + 33554432;
  if (ws_size < XOFF) {
    scan_all<<<2048, 256, 0, stream>>>(x, E, out);
    return;
  }
  unsigned* cnt1 = (unsigned*)ws;
  float* e2f = (float*)(ws + 64);
  double* e2d = (double*)(ws + 64 + 16384);
  char* ehi = ws + 64 + 16384 + 32768;
  unsigned* list1 = (unsigned*)(ehi + 2097152);
  char* xpack = (ws_size >= NEED_BIG) ? (ws + NEED_ET) : (char*)d_out;

  if (ws_size >= NEED_ET) {
    float* ETp = (float*)(ws + ET_OFF);
    Part* partp = (Part*)(ws + PART_OFF);
    fused_pack<<<2560, 256, 0, stream>>>(x, xpack, E, ehi, e2f, e2d, ETp, 1,
                                         cnt1);
    vq_main<<<512, 256, 40960, stream>>>(xpack, ehi, e2f, E, out, cnt1, list1);
    vq_exact_part<<<1024, 256, 0, stream>>>(x, ETp, e2d, partp, cnt1, list1);
    vq_combine2<<<256, 256, 0, stream>>>(partp, x, E, e2d, cnt1, list1, out);
  } else {
    fused_pack<<<2560, 256, 0, stream>>>(x, xpack, E, ehi, e2f, e2d, nullptr,
                                         0, cnt1);
    vq_main<<<512, 256, 40960, stream>>>(xpack, ehi, e2f, E, out, cnt1, list1);
    vq_exact_slow<<<1024, 256, 0, stream>>>(x, E, e2d, out, cnt1, list1, 0u);
  }
}

// Round 19
// 189.455 us; speedup vs baseline: 1.1039x; 1.0177x over previous
//
#include <hip/hip_runtime.h>

// VQ nearest-codeword, 2-tier (round-16 config + A-resident LDS in vq_main):
//  fused_pack: memset(cnt) + pack_x + pack_e + pack_et in ONE dispatch.
//  T1 vq_main: fp16 single-pass MFMA GEMM; A (64 rows x K=256, 32KB) staged
//      to LDS ONCE in the prologue (was re-staged 16x); B double-buffered
//      per k-step (proven 2-phase sync structure unchanged). Fused top-2.
//  T2: vq_exact_part (ET-coalesced partial argmin, 4-row group, kb unroll 4)
//      + vq_combine2 (combine partials + overflow scan).

typedef float f32x4 __attribute__((ext_vector_type(4)));
typedef _Float16 f16x8 __attribute__((ext_vector_type(8)));

#define TAU1 0.15f
#define LIST_CAP 65536u
#define PROWS 4096u

struct Part { double d; long long idx; };  // 16 B

__device__ __forceinline__ unsigned short f16b(float f) {
  _Float16 h = (_Float16)f;
  return __builtin_bit_cast(unsigned short, h);
}

__device__ __forceinline__ void gl16(char* lds, const char* g) {
  __builtin_amdgcn_global_load_lds(
      (const __attribute__((address_space(1))) void*)g,
      (__attribute__((address_space(3))) void*)lds, 16, 0, 0);
}

// ---- fused pack: blocks [0,2048) pack_x, [2048,2304) pack_e (+cnt zero),
//      [2304,2560) pack_et (skipped when has_et==0) ----
__global__ __launch_bounds__(256) void fused_pack(
    const float* __restrict__ x, char* xp, const float* __restrict__ E,
    char* __restrict__ ehi, float* __restrict__ e2f, double* __restrict__ e2d,
    float* __restrict__ ET, int has_et, unsigned* __restrict__ cnt1) {
  const int bx = blockIdx.x;
  const int tid = threadIdx.x;
  if (bx < 2048) {  // ---- pack_x body (proven) ----
    int gid = bx * 256 + tid;
    int row = gid >> 4, seg = gid & 15;
    const float4* xr = (const float4*)(x + (size_t)row * 256 + seg * 16);
    unsigned o[8];
#pragma unroll
    for (int q = 0; q < 4; ++q) {
      float4 f = xr[q];
      o[q * 2]     = (unsigned)f16b(f.x) | ((unsigned)f16b(f.y) << 16);
      o[q * 2 + 1] = (unsigned)f16b(f.z) | ((unsigned)f16b(f.w) << 16);
    }
    uint4* dst = (uint4*)(xp + (size_t)row * 1024 + seg * 32);
    dst[0] = make_uint4(o[0], o[1], o[2], o[3]);
    dst[1] = make_uint4(o[4], o[5], o[6], o[7]);
  } else if (bx < 2304) {  // ---- pack_e body (proven) + cnt zero ----
    if (bx == 2048 && tid == 0) *cnt1 = 0u;
    int vl = tid >> 4, seg = tid & 15;
    int v = (bx - 2048) * 16 + vl;
    const float4* er = (const float4*)(E + (size_t)v * 256 + seg * 16);
    unsigned oh[8];
    double s = 0.0;
#pragma unroll
    for (int q = 0; q < 4; ++q) {
      float4 f = er[q];
      float vf[4] = {f.x, f.y, f.z, f.w};
      unsigned short hb[4];
#pragma unroll
      for (int e = 0; e < 4; ++e) {
        float fv = vf[e];
        s += (double)fv * (double)fv;
        hb[e] = f16b(fv);
      }
      oh[q * 2]     = (unsigned)hb[0] | ((unsigned)hb[1] << 16);
      oh[q * 2 + 1] = (unsigned)hb[2] | ((unsigned)hb[3] << 16);
    }
    uint4* dh = (uint4*)(ehi + (size_t)v * 512 + seg * 32);
    dh[0] = make_uint4(oh[0], oh[1], oh[2], oh[3]);
    dh[1] = make_uint4(oh[4], oh[5], oh[6], oh[7]);
#pragma unroll
    for (int off = 1; off < 16; off <<= 1) s += __shfl_xor(s, off);
    if (seg == 0) { e2f[v] = (float)s; e2d[v] = s; }
  } else {  // ---- pack_et body (proven), flattened grid ----
    if (!has_et) return;
    __shared__ float tile[64][65];
    const int idx = bx - 2304;
    const int vt = (idx & 63) * 64;
    const int kt = (idx >> 6) * 64;
    const int r = tid >> 4, c4 = (tid & 15) * 4;
#pragma unroll
    for (int i = 0; i < 4; ++i) {
      float4 v4 =
          *(const float4*)(E + (size_t)(vt + r + i * 16) * 256 + kt + c4);
      tile[r + i * 16][c4] = v4.x;
      tile[r + i * 16][c4 + 1] = v4.y;
      tile[r + i * 16][c4 + 2] = v4.z;
      tile[r + i * 16][c4 + 3] = v4.w;
    }
    __syncthreads();
#pragma unroll
    for (int i = 0; i < 4; ++i) {
      int kk = r + i * 16;
      float4 o;
      o.x = tile[c4 + 0][kk];
      o.y = tile[c4 + 1][kk];
      o.z = tile[c4 + 2][kk];
      o.w = tile[c4 + 3][kk];
      *(float4*)(ET + (size_t)(kt + kk) * 4096 + vt + c4) = o;
    }
  }
}

// ---- T1 main: A resident in LDS (staged once), B dbuf per k-step ----
// LDS: A [0,32768) = [8 k-regions][4096 B]; B at 32768 + p*16384.
__global__ __launch_bounds__(256) void vq_main(
    const char* xpack, const char* __restrict__ epack,
    const float* __restrict__ e2f, const float* __restrict__ E,
    float* out, unsigned* __restrict__ cnt1, unsigned* __restrict__ list1) {
  extern __shared__ char smem[];
  const int tid = threadIdx.x;
  const int w = tid >> 6, lane = tid & 63;
  const int l15 = lane & 15, g = lane >> 4;
  const int rowbase = blockIdx.x * 64;

  // loader geometry (linear LDS dest, inverse-swizzled global source)
  const int rA = w * 16 + (lane >> 2);
  const int swz = (((lane & 3) ^ ((lane >> 2) & 3)) << 4);
  const char* aBase = xpack + (size_t)(rowbase + rA) * 1024 + swz;
  const char* bBase = epack + (size_t)(w * 64 + (lane >> 2)) * 512 + swz;
  const int ldA = w * 1024 + lane * 16;
  const int ldB = w * 4096 + lane * 16;

  // fragment read offsets (XOR-swizzled)
  const int fsw = ((g ^ (l15 & 3)) << 4);
  int aoff[4], boff[4];
#pragma unroll
  for (int mi = 0; mi < 4; ++mi) aoff[mi] = mi * 1024 + l15 * 64 + fsw;
#pragma unroll
  for (int ni = 0; ni < 4; ++ni)
    boff[ni] = 32768 + w * 4096 + ni * 1024 + l15 * 64 + fsw;

  f32x4 acc[4][4];
#pragma unroll
  for (int mi = 0; mi < 4; ++mi)
#pragma unroll
    for (int ni = 0; ni < 4; ++ni) acc[mi][ni] = (f32x4){0.f, 0.f, 0.f, 0.f};

  float m1[16], m2[16];
  int i1[16];
#pragma unroll
  for (int s = 0; s < 16; ++s) { m1[s] = 3.4e38f; m2[s] = 3.4e38f; i1[s] = 0; }

#define STAGE_B(p, coff, koff)                                              \
  do {                                                                      \
    _Pragma("unroll") for (int i_ = 0; i_ < 4; ++i_)                        \
        gl16(smem + 32768 + (p)*16384 + ldB + i_ * 1024,                    \
             bBase + i_ * 8192 + (coff) + (koff));                          \
  } while (0)

  // prologue: stage ALL of A (32 KB, proven round-12/13 geometry) + B(0,0)
#pragma unroll
  for (int k = 0; k < 8; ++k) gl16(smem + k * 4096 + ldA, aBase + k * 64);
  STAGE_B(0, (size_t)0, 0);
  __syncthreads();

#pragma unroll 1
  for (int c = 0; c < 16; ++c) {
    const size_t coff = (size_t)c * 131072;
#pragma unroll
    for (int k = 0; k < 8; ++k) {
      const int p = k & 1;
      if (!(c == 15 && k == 7)) {
        if (k == 7) STAGE_B(0, coff + 131072, 0);
        else STAGE_B(p ^ 1, coff, (k + 1) * 64);
      }
      const char* Ar = smem + k * 4096;          // A: per-k region, resident
      const char* Br = smem + boff[0] - boff[0]; // (unused base trick avoided)
      f16x8 a[4], b[4];
#pragma unroll
      for (int mi = 0; mi < 4; ++mi) a[mi] = *(const f16x8*)(Ar + aoff[mi]);
#pragma unroll
      for (int ni = 0; ni < 4; ++ni)
        b[ni] = *(const f16x8*)(smem + p * 16384 + boff[ni]);
#pragma unroll
      for (int mi = 0; mi < 4; ++mi)
#pragma unroll
        for (int ni = 0; ni < 4; ++ni)
          acc[mi][ni] = __builtin_amdgcn_mfma_f32_16x16x32_f16(
              a[mi], b[ni], acc[mi][ni], 0, 0, 0);
      __syncthreads();
    }
    // fused epilogue: distances + top-2, reset acc
    const int cb = c * 256 + w * 64;
#pragma unroll
    for (int ni = 0; ni < 4; ++ni) {
      const int col = cb + ni * 16 + l15;
      const float ev = e2f[col];
#pragma unroll
      for (int mi = 0; mi < 4; ++mi)
#pragma unroll
        for (int rg = 0; rg < 4; ++rg) {
          float d = fmaf(-2.0f, acc[mi][ni][rg], ev);
          const int s = mi * 4 + rg;
          bool better = d < m1[s];
          m2[s] = fminf(m2[s], better ? m1[s] : d);
          m1[s] = better ? d : m1[s];
          i1[s] = better ? col : i1[s];
          acc[mi][ni][rg] = 0.0f;
        }
    }
  }
#undef STAGE_B

  // butterfly merge across the 16 lanes sharing each row-set
#pragma unroll
  for (int s = 0; s < 16; ++s) {
#pragma unroll
    for (int off = 1; off < 16; off <<= 1) {
      float om1 = __shfl_xor(m1[s], off);
      float om2 = __shfl_xor(m2[s], off);
      int oi = __shfl_xor(i1[s], off);
      float nm2 = fminf(fminf(m2[s], om2), fmaxf(m1[s], om1));
      bool take = om1 < m1[s];
      m1[s] = take ? om1 : m1[s];
      i1[s] = take ? oi : i1[s];
      m2[s] = nm2;
    }
  }

  float* sm1 = (float*)smem;  // reuse A region (loop done)
  float* sm2 = (float*)(smem + 1024);
  int* si1 = (int*)(smem + 2048);
  unsigned* swin = (unsigned*)(smem + 3072);
  __syncthreads();
  if (l15 == 0) {
#pragma unroll
    for (int s = 0; s < 16; ++s) {
      int r = (s >> 2) * 16 + g * 4 + (s & 3);
      sm1[w * 64 + r] = m1[s];
      sm2[w * 64 + r] = m2[s];
      si1[w * 64 + r] = i1[s];
    }
  }
  __syncthreads();
  if (tid < 64) {
    int r = tid;
    float am1 = sm1[r], am2 = sm2[r];
    int ai = si1[r];
#pragma unroll
    for (int ww = 1; ww < 4; ++ww) {
      float om1 = sm1[ww * 64 + r], om2 = sm2[ww * 64 + r];
      int oi = si1[ww * 64 + r];
      float nm2 = fminf(fminf(am2, om2), fmaxf(am1, om1));
      bool take = om1 < am1;
      am1 = take ? om1 : am1;
      ai = take ? oi : ai;
      am2 = nm2;
    }
    swin[r] = (unsigned)ai;
    if (am2 - am1 < TAU1) {
      unsigned p = atomicAdd(cnt1, 1u);
      if (p < LIST_CAP) list1[p] = (unsigned)(rowbase + r);
    }
  }
  __syncthreads();
  {
    int r = tid >> 2, part = tid & 3;
    unsigned wv = swin[r];
    const float4* src = (const float4*)(E + (size_t)wv * 256 + part * 64);
    float4* dst = (float4*)(out + (size_t)(rowbase + r) * 256 + part * 64);
#pragma unroll
    for (int q = 0; q < 16; ++q) dst[q] = src[q];
  }
}

// ---- T2 Stage A: per (4-row group, 1024-cw quarter) partial argmin ----
// kb-loop unroll 4: 16 independent 16B L2 loads in flight (latency hiding).
__global__ __launch_bounds__(256) void vq_exact_part(
    const float* __restrict__ x, const float* __restrict__ ET,
    const double* __restrict__ e2d, Part* __restrict__ part,
    const unsigned* __restrict__ cnt1, const unsigned* __restrict__ list1) {
  __shared__ float xs[4][256];
  __shared__ double swd[16];
  __shared__ int swi[16];
  unsigned n = *cnt1;
  if (n > PROWS) n = PROWS;
  const unsigned nunits = ((n + 3) >> 2) << 2;  // 4 splits per group
  const int tid = threadIdx.x;
  const int wid = tid >> 6, lane = tid & 63;
  for (unsigned u = blockIdx.x; u < nunits; u += gridDim.x) {
    const unsigned g = u >> 2;
    const int s = u & 3;
    const unsigned base = g * 4;
    __syncthreads();  // protect shared reuse across iterations
#pragma unroll
    for (int j = 0; j < 4; ++j) {
      unsigned jj = base + (unsigned)j;
      unsigned row = list1[jj < n ? jj : (n - 1)];
      xs[j][tid] = x[(size_t)row * 256 + tid];
    }
    __syncthreads();
    double best[4];
    int bi[4];
#pragma unroll
    for (int j = 0; j < 4; ++j) { best[j] = 1e300; bi[j] = 1 << 30; }
    {
      const int vb = s * 1024 + tid * 4;
      const char* ep = (const char*)(ET + vb);  // row stride 16384 B
      double a[4][4];
#pragma unroll
      for (int j = 0; j < 4; ++j)
#pragma unroll
        for (int c = 0; c < 4; ++c) a[j][c] = 0.0;
#pragma unroll 4
      for (int kb = 0; kb < 256; kb += 4) {
        float4 qf0 = *(const float4*)(ep + (size_t)(kb + 0) * 16384);
        float4 qf1 = *(const float4*)(ep + (size_t)(kb + 1) * 16384);
        float4 qf2 = *(const float4*)(ep + (size_t)(kb + 2) * 16384);
        float4 qf3 = *(const float4*)(ep + (size_t)(kb + 3) * 16384);
        double q0x = qf0.x, q0y = qf0.y, q0z = qf0.z, q0w = qf0.w;
        double q1x = qf1.x, q1y = qf1.y, q1z = qf1.z, q1w = qf1.w;
        double q2x = qf2.x, q2y = qf2.y, q2z = qf2.z, q2w = qf2.w;
        double q3x = qf3.x, q3y = qf3.y, q3z = qf3.z, q3w = qf3.w;
#pragma unroll
        for (int j = 0; j < 4; ++j) {
          float4 xv = *(const float4*)&xs[j][kb];  // broadcast b128 LDS read
          double x0 = xv.x, x1 = xv.y, x2 = xv.z, x3 = xv.w;
          a[j][0] += x0 * q0x + x1 * q1x + x2 * q2x + x3 * q3x;
          a[j][1] += x0 * q0y + x1 * q1y + x2 * q2y + x3 * q3y;
          a[j][2] += x0 * q0z + x1 * q1z + x2 * q2z + x3 * q3z;
          a[j][3] += x0 * q0w + x1 * q1w + x2 * q2w + x3 * q3w;
        }
      }
#pragma unroll
      for (int c = 0; c < 4; ++c) {
        double e2 = e2d[vb + c];
        int v = vb + c;
#pragma unroll
        for (int j = 0; j < 4; ++j) {
          double d = e2 - 2.0 * a[j][c];
          if (d < best[j] || (d == best[j] && v < bi[j])) {
            best[j] = d; bi[j] = v;
          }
        }
      }
    }
    // wave butterfly reduce per row, then cross-wave via LDS
#pragma unroll
    for (int j = 0; j < 4; ++j) {
#pragma unroll
      for (int off = 1; off < 64; off <<= 1) {
        double ob = __shfl_xor(best[j], off);
        int oi = __shfl_xor(bi[j], off);
        if (ob < best[j] || (ob == best[j] && oi < bi[j])) {
          best[j] = ob; bi[j] = oi;
        }
      }
      if (lane == 0) { swd[wid * 4 + j] = best[j]; swi[wid * 4 + j] = bi[j]; }
    }
    __syncthreads();
    if (tid < 4) {
      double b = swd[tid];
      int v = swi[tid];
#pragma unroll
      for (int ww = 1; ww < 4; ++ww) {
        double ob = swd[ww * 4 + tid];
        int oi = swi[ww * 4 + tid];
        if (ob < b || (ob == b && oi < v)) { b = ob; v = oi; }
      }
      unsigned i = base + (unsigned)tid;
      if (i < n) {
        Part pw;
        pw.d = b;
        pw.idx = (long long)v;
        part[(size_t)i * 4 + s] = pw;
      }
    }
  }
}

// ---- T2 Stage B + overflow: combine partials; slow-scan rows >= PROWS ----
__global__ __launch_bounds__(256) void vq_combine2(
    const Part* __restrict__ part, const float* __restrict__ x,
    const float* __restrict__ E, const double* __restrict__ e2d,
    const unsigned* __restrict__ cnt1, const unsigned* __restrict__ list1,
    float* __restrict__ out) {
  unsigned ntot = *cnt1;
  if (ntot > LIST_CAP) ntot = LIST_CAP;
  unsigned n = ntot > PROWS ? PROWS : ntot;
  const int tid = threadIdx.x;
  // phase 1: combine 4 partials per row, gather-write (proven body)
  {
    const int lr = tid >> 6, lane = tid & 63;
    for (unsigned i = blockIdx.x * 4u + (unsigned)lr; i < n;
         i += gridDim.x * 4u) {
      const Part* p = part + (size_t)i * 4;
      double b = p[0].d;
      long long v = p[0].idx;
#pragma unroll
      for (int s = 1; s < 4; ++s) {
        double ob = p[s].d;
        long long oi = p[s].idx;
        if (ob < b || (ob == b && oi < v)) { b = ob; v = oi; }
      }
      unsigned row = list1[i];
      float4 v4 = ((const float4*)(E + (size_t)v * 256))[lane];
      ((float4*)(out + (size_t)row * 256))[lane] = v4;
    }
  }
  // phase 2: overflow rows [PROWS, ntot) — full exact scan (normally no-op)
  if (ntot <= PROWS) return;
  __shared__ float4 xs[64];
  __shared__ double sd[256];
  __shared__ int si[256];
  for (unsigned i = PROWS + blockIdx.x; i < ntot; i += gridDim.x) {
    unsigned row = list1[i];
    __syncthreads();
    if (tid < 64) xs[tid] = ((const float4*)(x + (size_t)row * 256))[tid];
    __syncthreads();
    double best = 1e300;
    int bi = 1 << 30;
#pragma unroll 1
    for (int jg = 0; jg < 4; ++jg) {
      const int v0 = tid + jg * 1024;
      const float4* e0 = (const float4*)(E + (size_t)v0 * 256);
      const float4* e1 = (const float4*)(E + (size_t)(v0 + 256) * 256);
      const float4* e2 = (const float4*)(E + (size_t)(v0 + 512) * 256);
      const float4* e3 = (const float4*)(E + (size_t)(v0 + 768) * 256);
      double a0 = 0, a1 = 0, a2 = 0, a3 = 0;
      double b0 = 0, b1 = 0, b2 = 0, b3 = 0;
#pragma unroll 4
      for (int k4 = 0; k4 < 64; ++k4) {
        float4 xv = xs[k4];
        float4 q0 = e0[k4], q1 = e1[k4], q2 = e2[k4], q3 = e3[k4];
        a0 += (double)xv.x * q0.x + (double)xv.z * q0.z;
        b0 += (double)xv.y * q0.y + (double)xv.w * q0.w;
        a1 += (double)xv.x * q1.x + (double)xv.z * q1.z;
        b1 += (double)xv.y * q1.y + (double)xv.w * q1.w;
        a2 += (double)xv.x * q2.x + (double)xv.z * q2.z;
        b2 += (double)xv.y * q2.y + (double)xv.w * q2.w;
        a3 += (double)xv.x * q3.x + (double)xv.z * q3.z;
        b3 += (double)xv.y * q3.y + (double)xv.w * q3.w;
      }
      double d0 = e2d[v0] - 2.0 * (a0 + b0);
      double d1 = e2d[v0 + 256] - 2.0 * (a1 + b1);
      double d2 = e2d[v0 + 512] - 2.0 * (a2 + b2);
      double d3 = e2d[v0 + 768] - 2.0 * (a3 + b3);
      if (d0 < best || (d0 == best && v0 < bi)) { best = d0; bi = v0; }
      if (d1 < best || (d1 == best && v0 + 256 < bi)) { best = d1; bi = v0 + 256; }
      if (d2 < best || (d2 == best && v0 + 512 < bi)) { best = d2; bi = v0 + 512; }
      if (d3 < best || (d3 == best && v0 + 768 < bi)) { best = d3; bi = v0 + 768; }
    }
    sd[tid] = best;
    si[tid] = bi;
    __syncthreads();
    for (int s = 128; s > 0; s >>= 1) {
      if (tid < s) {
        double ob = sd[tid + s];
        int oi = si[tid + s];
        if (ob < sd[tid] || (ob == sd[tid] && oi < si[tid])) {
          sd[tid] = ob; si[tid] = oi;
        }
      }
      __syncthreads();
    }
    int win = si[0];
    if (tid < 64) {
      float4 v4 = ((const float4*)(E + (size_t)win * 256))[tid];
      ((float4*)(out + (size_t)row * 256))[tid] = v4;
    }
  }
}

// ---- T2 fallback for medium ws (proven): rows [start, n) direct from E ----
__global__ __launch_bounds__(256) void vq_exact_slow(
    const float* __restrict__ x, const float* __restrict__ E,
    const double* __restrict__ e2d, float* __restrict__ out,
    const unsigned* __restrict__ cnt1, const unsigned* __restrict__ list1,
    unsigned start) {
  __shared__ float4 xs[64];
  __shared__ double sd[256];
  __shared__ int si[256];
  unsigned n = *cnt1;
  if (n > LIST_CAP) n = LIST_CAP;
  const int tid = threadIdx.x;
  for (unsigned i = start + blockIdx.x; i < n; i += gridDim.x) {
    unsigned row = list1[i];
    __syncthreads();
    if (tid < 64) xs[tid] = ((const float4*)(x + (size_t)row * 256))[tid];
    __syncthreads();
    double best = 1e300;
    int bi = 1 << 30;
#pragma unroll 1
    for (int jg = 0; jg < 4; ++jg) {
      const int v0 = tid + jg * 1024;
      const float4* e0 = (const float4*)(E + (size_t)v0 * 256);
      const float4* e1 = (const float4*)(E + (size_t)(v0 + 256) * 256);
      const float4* e2 = (const float4*)(E + (size_t)(v0 + 512) * 256);
      const float4* e3 = (const float4*)(E + (size_t)(v0 + 768) * 256);
      double a0 = 0, a1 = 0, a2 = 0, a3 = 0;
      double b0 = 0, b1 = 0, b2 = 0, b3 = 0;
#pragma unroll 4
      for (int k4 = 0; k4 < 64; ++k4) {
        float4 xv = xs[k4];
        float4 q0 = e0[k4], q1 = e1[k4], q2 = e2[k4], q3 = e3[k4];
        a0 += (double)xv.x * q0.x + (double)xv.z * q0.z;
        b0 += (double)xv.y * q0.y + (double)xv.w * q0.w;
        a1 += (double)xv.x * q1.x + (double)xv.z * q1.z;
        b1 += (double)xv.y * q1.y + (double)xv.w * q1.w;
        a2 += (double)xv.x * q2.x + (double)xv.z * q2.z;
        b2 += (double)xv.y * q2.y + (double)xv.w * q2.w;
        a3 += (double)xv.x * q3.x + (double)xv.z * q3.z;
        b3 += (double)xv.y * q3.y + (double)xv.w * q3.w;
      }
      double d0 = e2d[v0] - 2.0 * (a0 + b0);
      double d1 = e2d[v0 + 256] - 2.0 * (a1 + b1);
      double d2 = e2d[v0 + 512] - 2.0 * (a2 + b2);
      double d3 = e2d[v0 + 768] - 2.0 * (a3 + b3);
      if (d0 < best || (d0 == best && v0 < bi)) { best = d0; bi = v0; }
      if (d1 < best || (d1 == best && v0 + 256 < bi)) { best = d1; bi = v0 + 256; }
      if (d2 < best || (d2 == best && v0 + 512 < bi)) { best = d2; bi = v0 + 512; }
      if (d3 < best || (d3 == best && v0 + 768 < bi)) { best = d3; bi = v0 + 768; }
    }
    sd[tid] = best;
    si[tid] = bi;
    __syncthreads();
    for (int s = 128; s > 0; s >>= 1) {
      if (tid < s) {
        double ob = sd[tid + s];
        int oi = si[tid + s];
        if (ob < sd[tid] || (ob == sd[tid] && oi < si[tid])) {
          sd[tid] = ob; si[tid] = oi;
        }
      }
      __syncthreads();
    }
    int win = si[0];
    if (tid < 64) {
      float4 v4 = ((const float4*)(E + (size_t)win * 256))[tid];
      ((float4*)(out + (size_t)row * 256))[tid] = v4;
    }
  }
}

// ---- insurance: exact fp64 scan of ALL rows (only if ws too small) ----
__global__ void scan_all(const float* __restrict__ x,
                         const float* __restrict__ E, float* out) {
  __shared__ double sd[256];
  __shared__ int si[256];
  for (int row = blockIdx.x; row < 32768; row += gridDim.x) {
    const float* xr = x + (size_t)row * 256;
    double best = 1e300;
    int bi = 1 << 30;
    for (int v = threadIdx.x; v < 4096; v += 256) {
      const float* ev = E + (size_t)v * 256;
      double a0 = 0, a1 = 0, a2 = 0, a3 = 0;
      for (int k = 0; k < 256; k += 4) {
        double d0 = (double)xr[k] - (double)ev[k];
        double d1 = (double)xr[k + 1] - (double)ev[k + 1];
        double d2 = (double)xr[k + 2] - (double)ev[k + 2];
        double d3 = (double)xr[k + 3] - (double)ev[k + 3];
        a0 += d0 * d0; a1 += d1 * d1; a2 += d2 * d2; a3 += d3 * d3;
      }
      double d = (a0 + a1) + (a2 + a3);
      if (d < best || (d == best && v < bi)) { best = d; bi = v; }
    }
    sd[threadIdx.x] = best; si[threadIdx.x] = bi;
    __syncthreads();
    for (int s = 128; s > 0; s >>= 1) {
      if ((int)threadIdx.x < s) {
        double ob = sd[threadIdx.x + s];
        int oi = si[threadIdx.x + s];
        if (ob < sd[threadIdx.x] ||
            (ob == sd[threadIdx.x] && oi < si[threadIdx.x])) {
          sd[threadIdx.x] = ob; si[threadIdx.x] = oi;
        }
      }
      __syncthreads();
    }
    int win = si[0];
    __syncthreads();
    out[(size_t)row * 256 + threadIdx.x] = E[(size_t)win * 256 + threadIdx.x];
  }
}

extern "C" void kernel_launch(void* const* d_in, const int* in_sizes, int n_in,
                              void* d_out, int out_size, void* d_ws,
                              size_t ws_size, hipStream_t stream) {
  (void)in_sizes; (void)n_in; (void)out_size;
  const float* x = (const float*)d_in[0];
  const float* E = (const float*)d_in[1];
  float* out = (float*)d_out;
  char* ws = (char*)d_ws;
  // ws: [cnt 64][e2f 16K][e2d 32K][ehi 2M][list1 256K][ET 4M][part 256K][xpack 32M?]
  const size_t XOFF = 64 + 16384 + 32768 + 2097152 + 262144;  // 2408512
  const size_t ET_OFF = XOFF;
  const size_t PART_OFF = ET_OFF + 4194304;
  const size_t NEED_ET = PART_OFF + (size_t)PROWS * 4 * sizeof(Part);  // +256K
  const size_t NEED_BIG = NEED_ET + 33554432;
  if (ws_size < XOFF) {
    scan_all<<<2048, 256, 0, stream>>>(x, E, out);
    return;
  }
  unsigned* cnt1 = (unsigned*)ws;
  float* e2f = (float*)(ws + 64);
  double* e2d = (double*)(ws + 64 + 16384);
  char* ehi = ws + 64 + 16384 + 32768;
  unsigned* list1 = (unsigned*)(ehi + 2097152);
  char* xpack = (ws_size >= NEED_BIG) ? (ws + NEED_ET) : (char*)d_out;

  if (ws_size >= NEED_ET) {
    float* ETp = (float*)(ws + ET_OFF);
    Part* partp = (Part*)(ws + PART_OFF);
    fused_pack<<<2560, 256, 0, stream>>>(x, xpack, E, ehi, e2f, e2d, ETp, 1,
                                         cnt1);
    vq_main<<<512, 256, 65536, stream>>>(xpack, ehi, e2f, E, out, cnt1, list1);
    vq_exact_part<<<1024, 256, 0, stream>>>(x, ETp, e2d, partp, cnt1, list1);
    vq_combine2<<<256, 256, 0, stream>>>(partp, x, E, e2d, cnt1, list1, out);
  } else {
    fused_pack<<<2560, 256, 0, stream>>>(x, xpack, E, ehi, e2f, e2d, nullptr,
                                         0, cnt1);
    vq_main<<<512, 256, 65536, stream>>>(xpack, ehi, e2f, E, out, cnt1, list1);
    vq_exact_slow<<<1024, 256, 0, stream>>>(x, E, e2d, out, cnt1, list1, 0u);
  }
}

// Round 20
// 189.223 us; speedup vs baseline: 1.1052x; 1.0012x over previous
//
#include <hip/hip_runtime.h>

// VQ nearest-codeword, 2-tier (round-19 config + 8-way col-split exact tier):
//  fused_pack: memset(cnt) + pack_x + pack_e + pack_et in ONE dispatch.
//  T1 vq_main: fp16 single-pass MFMA GEMM; A resident in LDS (staged once),
//      B double-buffered per k-step (proven). Fused per-row top-2.
//  T2: vq_exact_part (unit = 4-row group x 512-col eighth; 1152 units for
//      2x TLP; float2 column loads, a[4][2] acc) + vq_combine2 (8 partials).

typedef float f32x4 __attribute__((ext_vector_type(4)));
typedef _Float16 f16x8 __attribute__((ext_vector_type(8)));

#define TAU1 0.15f
#define LIST_CAP 65536u
#define PROWS 2048u  // 8 partials/row @16B -> 256KB part buffer (layout kept)

struct Part { double d; long long idx; };  // 16 B

__device__ __forceinline__ unsigned short f16b(float f) {
  _Float16 h = (_Float16)f;
  return __builtin_bit_cast(unsigned short, h);
}

__device__ __forceinline__ void gl16(char* lds, const char* g) {
  __builtin_amdgcn_global_load_lds(
      (const __attribute__((address_space(1))) void*)g,
      (__attribute__((address_space(3))) void*)lds, 16, 0, 0);
}

// ---- fused pack: blocks [0,2048) pack_x, [2048,2304) pack_e (+cnt zero),
//      [2304,2560) pack_et (skipped when has_et==0) ----
__global__ __launch_bounds__(256) void fused_pack(
    const float* __restrict__ x, char* xp, const float* __restrict__ E,
    char* __restrict__ ehi, float* __restrict__ e2f, double* __restrict__ e2d,
    float* __restrict__ ET, int has_et, unsigned* __restrict__ cnt1) {
  const int bx = blockIdx.x;
  const int tid = threadIdx.x;
  if (bx < 2048) {  // ---- pack_x body (proven) ----
    int gid = bx * 256 + tid;
    int row = gid >> 4, seg = gid & 15;
    const float4* xr = (const float4*)(x + (size_t)row * 256 + seg * 16);
    unsigned o[8];
#pragma unroll
    for (int q = 0; q < 4; ++q) {
      float4 f = xr[q];
      o[q * 2]     = (unsigned)f16b(f.x) | ((unsigned)f16b(f.y) << 16);
      o[q * 2 + 1] = (unsigned)f16b(f.z) | ((unsigned)f16b(f.w) << 16);
    }
    uint4* dst = (uint4*)(xp + (size_t)row * 1024 + seg * 32);
    dst[0] = make_uint4(o[0], o[1], o[2], o[3]);
    dst[1] = make_uint4(o[4], o[5], o[6], o[7]);
  } else if (bx < 2304) {  // ---- pack_e body (proven) + cnt zero ----
    if (bx == 2048 && tid == 0) *cnt1 = 0u;
    int vl = tid >> 4, seg = tid & 15;
    int v = (bx - 2048) * 16 + vl;
    const float4* er = (const float4*)(E + (size_t)v * 256 + seg * 16);
    unsigned oh[8];
    double s = 0.0;
#pragma unroll
    for (int q = 0; q < 4; ++q) {
      float4 f = er[q];
      float vf[4] = {f.x, f.y, f.z, f.w};
      unsigned short hb[4];
#pragma unroll
      for (int e = 0; e < 4; ++e) {
        float fv = vf[e];
        s += (double)fv * (double)fv;
        hb[e] = f16b(fv);
      }
      oh[q * 2]     = (unsigned)hb[0] | ((unsigned)hb[1] << 16);
      oh[q * 2 + 1] = (unsigned)hb[2] | ((unsigned)hb[3] << 16);
    }
    uint4* dh = (uint4*)(ehi + (size_t)v * 512 + seg * 32);
    dh[0] = make_uint4(oh[0], oh[1], oh[2], oh[3]);
    dh[1] = make_uint4(oh[4], oh[5], oh[6], oh[7]);
#pragma unroll
    for (int off = 1; off < 16; off <<= 1) s += __shfl_xor(s, off);
    if (seg == 0) { e2f[v] = (float)s; e2d[v] = s; }
  } else {  // ---- pack_et body (proven), flattened grid ----
    if (!has_et) return;
    __shared__ float tile[64][65];
    const int idx = bx - 2304;
    const int vt = (idx & 63) * 64;
    const int kt = (idx >> 6) * 64;
    const int r = tid >> 4, c4 = (tid & 15) * 4;
#pragma unroll
    for (int i = 0; i < 4; ++i) {
      float4 v4 =
          *(const float4*)(E + (size_t)(vt + r + i * 16) * 256 + kt + c4);
      tile[r + i * 16][c4] = v4.x;
      tile[r + i * 16][c4 + 1] = v4.y;
      tile[r + i * 16][c4 + 2] = v4.z;
      tile[r + i * 16][c4 + 3] = v4.w;
    }
    __syncthreads();
#pragma unroll
    for (int i = 0; i < 4; ++i) {
      int kk = r + i * 16;
      float4 o;
      o.x = tile[c4 + 0][kk];
      o.y = tile[c4 + 1][kk];
      o.z = tile[c4 + 2][kk];
      o.w = tile[c4 + 3][kk];
      *(float4*)(ET + (size_t)(kt + kk) * 4096 + vt + c4) = o;
    }
  }
}

// ---- T1 main: A resident in LDS (staged once), B dbuf per k-step ----
// LDS: A [0,32768) = [8 k-regions][4096 B]; B at 32768 + p*16384.
__global__ __launch_bounds__(256) void vq_main(
    const char* xpack, const char* __restrict__ epack,
    const float* __restrict__ e2f, const float* __restrict__ E,
    float* out, unsigned* __restrict__ cnt1, unsigned* __restrict__ list1) {
  extern __shared__ char smem[];
  const int tid = threadIdx.x;
  const int w = tid >> 6, lane = tid & 63;
  const int l15 = lane & 15, g = lane >> 4;
  const int rowbase = blockIdx.x * 64;

  // loader geometry (linear LDS dest, inverse-swizzled global source)
  const int rA = w * 16 + (lane >> 2);
  const int swz = (((lane & 3) ^ ((lane >> 2) & 3)) << 4);
  const char* aBase = xpack + (size_t)(rowbase + rA) * 1024 + swz;
  const char* bBase = epack + (size_t)(w * 64 + (lane >> 2)) * 512 + swz;
  const int ldA = w * 1024 + lane * 16;
  const int ldB = w * 4096 + lane * 16;

  // fragment read offsets (XOR-swizzled)
  const int fsw = ((g ^ (l15 & 3)) << 4);
  int aoff[4], boff[4];
#pragma unroll
  for (int mi = 0; mi < 4; ++mi) aoff[mi] = mi * 1024 + l15 * 64 + fsw;
#pragma unroll
  for (int ni = 0; ni < 4; ++ni)
    boff[ni] = 32768 + w * 4096 + ni * 1024 + l15 * 64 + fsw;

  f32x4 acc[4][4];
#pragma unroll
  for (int mi = 0; mi < 4; ++mi)
#pragma unroll
    for (int ni = 0; ni < 4; ++ni) acc[mi][ni] = (f32x4){0.f, 0.f, 0.f, 0.f};

  float m1[16], m2[16];
  int i1[16];
#pragma unroll
  for (int s = 0; s < 16; ++s) { m1[s] = 3.4e38f; m2[s] = 3.4e38f; i1[s] = 0; }

#define STAGE_B(p, coff, koff)                                              \
  do {                                                                      \
    _Pragma("unroll") for (int i_ = 0; i_ < 4; ++i_)                        \
        gl16(smem + 32768 + (p)*16384 + ldB + i_ * 1024,                    \
             bBase + i_ * 8192 + (coff) + (koff));                          \
  } while (0)

  // prologue: stage ALL of A (32 KB) + B(chunk0, k0)
#pragma unroll
  for (int k = 0; k < 8; ++k) gl16(smem + k * 4096 + ldA, aBase + k * 64);
  STAGE_B(0, (size_t)0, 0);
  __syncthreads();

#pragma unroll 1
  for (int c = 0; c < 16; ++c) {
    const size_t coff = (size_t)c * 131072;
#pragma unroll
    for (int k = 0; k < 8; ++k) {
      const int p = k & 1;
      if (!(c == 15 && k == 7)) {
        if (k == 7) STAGE_B(0, coff + 131072, 0);
        else STAGE_B(p ^ 1, coff, (k + 1) * 64);
      }
      const char* Ar = smem + k * 4096;  // A: per-k region, resident
      f16x8 a[4], b[4];
#pragma unroll
      for (int mi = 0; mi < 4; ++mi) a[mi] = *(const f16x8*)(Ar + aoff[mi]);
#pragma unroll
      for (int ni = 0; ni < 4; ++ni)
        b[ni] = *(const f16x8*)(smem + p * 16384 + boff[ni]);
#pragma unroll
      for (int mi = 0; mi < 4; ++mi)
#pragma unroll
        for (int ni = 0; ni < 4; ++ni)
          acc[mi][ni] = __builtin_amdgcn_mfma_f32_16x16x32_f16(
              a[mi], b[ni], acc[mi][ni], 0, 0, 0);
      __syncthreads();
    }
    // fused epilogue: distances + top-2, reset acc
    const int cb = c * 256 + w * 64;
#pragma unroll
    for (int ni = 0; ni < 4; ++ni) {
      const int col = cb + ni * 16 + l15;
      const float ev = e2f[col];
#pragma unroll
      for (int mi = 0; mi < 4; ++mi)
#pragma unroll
        for (int rg = 0; rg < 4; ++rg) {
          float d = fmaf(-2.0f, acc[mi][ni][rg], ev);
          const int s = mi * 4 + rg;
          bool better = d < m1[s];
          m2[s] = fminf(m2[s], better ? m1[s] : d);
          m1[s] = better ? d : m1[s];
          i1[s] = better ? col : i1[s];
          acc[mi][ni][rg] = 0.0f;
        }
    }
  }
#undef STAGE_B

  // butterfly merge across the 16 lanes sharing each row-set
#pragma unroll
  for (int s = 0; s < 16; ++s) {
#pragma unroll
    for (int off = 1; off < 16; off <<= 1) {
      float om1 = __shfl_xor(m1[s], off);
      float om2 = __shfl_xor(m2[s], off);
      int oi = __shfl_xor(i1[s], off);
      float nm2 = fminf(fminf(m2[s], om2), fmaxf(m1[s], om1));
      bool take = om1 < m1[s];
      m1[s] = take ? om1 : m1[s];
      i1[s] = take ? oi : i1[s];
      m2[s] = nm2;
    }
  }

  float* sm1 = (float*)smem;  // reuse A region (loop done)
  float* sm2 = (float*)(smem + 1024);
  int* si1 = (int*)(smem + 2048);
  unsigned* swin = (unsigned*)(smem + 3072);
  __syncthreads();
  if (l15 == 0) {
#pragma unroll
    for (int s = 0; s < 16; ++s) {
      int r = (s >> 2) * 16 + g * 4 + (s & 3);
      sm1[w * 64 + r] = m1[s];
      sm2[w * 64 + r] = m2[s];
      si1[w * 64 + r] = i1[s];
    }
  }
  __syncthreads();
  if (tid < 64) {
    int r = tid;
    float am1 = sm1[r], am2 = sm2[r];
    int ai = si1[r];
#pragma unroll
    for (int ww = 1; ww < 4; ++ww) {
      float om1 = sm1[ww * 64 + r], om2 = sm2[ww * 64 + r];
      int oi = si1[ww * 64 + r];
      float nm2 = fminf(fminf(am2, om2), fmaxf(am1, om1));
      bool take = om1 < am1;
      am1 = take ? om1 : am1;
      ai = take ? oi : ai;
      am2 = nm2;
    }
    swin[r] = (unsigned)ai;
    if (am2 - am1 < TAU1) {
      unsigned p = atomicAdd(cnt1, 1u);
      if (p < LIST_CAP) list1[p] = (unsigned)(rowbase + r);
    }
  }
  __syncthreads();
  {
    int r = tid >> 2, part = tid & 3;
    unsigned wv = swin[r];
    const float4* src = (const float4*)(E + (size_t)wv * 256 + part * 64);
    float4* dst = (float4*)(out + (size_t)(rowbase + r) * 256 + part * 64);
#pragma unroll
    for (int q = 0; q < 16; ++q) dst[q] = src[q];
  }
}

// ---- T2 Stage A: per (4-row group, 512-col eighth) partial argmin ----
// 1152 units for 2x TLP; each thread owns 2 cols (float2 loads), a[4][2].
__global__ __launch_bounds__(256) void vq_exact_part(
    const float* __restrict__ x, const float* __restrict__ ET,
    const double* __restrict__ e2d, Part* __restrict__ part,
    const unsigned* __restrict__ cnt1, const unsigned* __restrict__ list1) {
  __shared__ float xs[4][256];
  __shared__ double swd[16];
  __shared__ int swi[16];
  unsigned n = *cnt1;
  if (n > PROWS) n = PROWS;
  const unsigned ngroups = (n + 3) >> 2;
  const unsigned nunits = ngroups << 3;  // 8 col-eighths per group
  const int tid = threadIdx.x;
  const int wid = tid >> 6, lane = tid & 63;
  for (unsigned u = blockIdx.x; u < nunits; u += gridDim.x) {
    const unsigned g = u >> 3;
    const int s = u & 7;
    const unsigned base = g * 4;
    __syncthreads();  // protect shared reuse across iterations
#pragma unroll
    for (int j = 0; j < 4; ++j) {
      unsigned jj = base + (unsigned)j;
      unsigned row = list1[jj < n ? jj : (n - 1)];
      xs[j][tid] = x[(size_t)row * 256 + tid];
    }
    __syncthreads();
    double best[4];
    int bi[4];
#pragma unroll
    for (int j = 0; j < 4; ++j) { best[j] = 1e300; bi[j] = 1 << 30; }
    {
      const int vb = s * 512 + tid * 2;
      const char* ep = (const char*)(ET + vb);  // row stride 16384 B
      double a[4][2];
#pragma unroll
      for (int j = 0; j < 4; ++j) { a[j][0] = 0.0; a[j][1] = 0.0; }
#pragma unroll 4
      for (int kb = 0; kb < 256; kb += 4) {
        float2 qf0 = *(const float2*)(ep + (size_t)(kb + 0) * 16384);
        float2 qf1 = *(const float2*)(ep + (size_t)(kb + 1) * 16384);
        float2 qf2 = *(const float2*)(ep + (size_t)(kb + 2) * 16384);
        float2 qf3 = *(const float2*)(ep + (size_t)(kb + 3) * 16384);
        double q0x = qf0.x, q0y = qf0.y;
        double q1x = qf1.x, q1y = qf1.y;
        double q2x = qf2.x, q2y = qf2.y;
        double q3x = qf3.x, q3y = qf3.y;
#pragma unroll
        for (int j = 0; j < 4; ++j) {
          float4 xv = *(const float4*)&xs[j][kb];  // broadcast b128 LDS read
          double x0 = xv.x, x1 = xv.y, x2 = xv.z, x3 = xv.w;
          a[j][0] += x0 * q0x + x1 * q1x + x2 * q2x + x3 * q3x;
          a[j][1] += x0 * q0y + x1 * q1y + x2 * q2y + x3 * q3y;
        }
      }
#pragma unroll
      for (int c = 0; c < 2; ++c) {
        double e2 = e2d[vb + c];
        int v = vb + c;
#pragma unroll
        for (int j = 0; j < 4; ++j) {
          double d = e2 - 2.0 * a[j][c];
          if (d < best[j] || (d == best[j] && v < bi[j])) {
            best[j] = d; bi[j] = v;
          }
        }
      }
    }
    // wave butterfly reduce per row, then cross-wave via LDS
#pragma unroll
    for (int j = 0; j < 4; ++j) {
#pragma unroll
      for (int off = 1; off < 64; off <<= 1) {
        double ob = __shfl_xor(best[j], off);
        int oi = __shfl_xor(bi[j], off);
        if (ob < best[j] || (ob == best[j] && oi < bi[j])) {
          best[j] = ob; bi[j] = oi;
        }
      }
      if (lane == 0) { swd[wid * 4 + j] = best[j]; swi[wid * 4 + j] = bi[j]; }
    }
    __syncthreads();
    if (tid < 4) {
      double b = swd[tid];
      int v = swi[tid];
#pragma unroll
      for (int ww = 1; ww < 4; ++ww) {
        double ob = swd[ww * 4 + tid];
        int oi = swi[ww * 4 + tid];
        if (ob < b || (ob == b && oi < v)) { b = ob; v = oi; }
      }
      unsigned i = base + (unsigned)tid;
      if (i < n) {
        Part pw;
        pw.d = b;
        pw.idx = (long long)v;
        part[(size_t)i * 8 + s] = pw;
      }
    }
  }
}

// ---- T2 Stage B + overflow: combine 8 partials; slow-scan rows >= PROWS ----
__global__ __launch_bounds__(256) void vq_combine2(
    const Part* __restrict__ part, const float* __restrict__ x,
    const float* __restrict__ E, const double* __restrict__ e2d,
    const unsigned* __restrict__ cnt1, const unsigned* __restrict__ list1,
    float* __restrict__ out) {
  unsigned ntot = *cnt1;
  if (ntot > LIST_CAP) ntot = LIST_CAP;
  unsigned n = ntot > PROWS ? PROWS : ntot;
  const int tid = threadIdx.x;
  // phase 1: combine 8 partials per row, gather-write
  {
    const int lr = tid >> 6, lane = tid & 63;
    for (unsigned i = blockIdx.x * 4u + (unsigned)lr; i < n;
         i += gridDim.x * 4u) {
      const Part* p = part + (size_t)i * 8;
      double b = p[0].d;
      long long v = p[0].idx;
#pragma unroll
      for (int s = 1; s < 8; ++s) {
        double ob = p[s].d;
        long long oi = p[s].idx;
        if (ob < b || (ob == b && oi < v)) { b = ob; v = oi; }
      }
      unsigned row = list1[i];
      float4 v4 = ((const float4*)(E + (size_t)v * 256))[lane];
      ((float4*)(out + (size_t)row * 256))[lane] = v4;
    }
  }
  // phase 2: overflow rows [PROWS, ntot) — full exact scan (normally no-op)
  if (ntot <= PROWS) return;
  __shared__ float4 xs[64];
  __shared__ double sd[256];
  __shared__ int si[256];
  for (unsigned i = PROWS + blockIdx.x; i < ntot; i += gridDim.x) {
    unsigned row = list1[i];
    __syncthreads();
    if (tid < 64) xs[tid] = ((const float4*)(x + (size_t)row * 256))[tid];
    __syncthreads();
    double best = 1e300;
    int bi = 1 << 30;
#pragma unroll 1
    for (int jg = 0; jg < 4; ++jg) {
      const int v0 = tid + jg * 1024;
      const float4* e0 = (const float4*)(E + (size_t)v0 * 256);
      const float4* e1 = (const float4*)(E + (size_t)(v0 + 256) * 256);
      const float4* e2 = (const float4*)(E + (size_t)(v0 + 512) * 256);
      const float4* e3 = (const float4*)(E + (size_t)(v0 + 768) * 256);
      double a0 = 0, a1 = 0, a2 = 0, a3 = 0;
      double b0 = 0, b1 = 0, b2 = 0, b3 = 0;
#pragma unroll 4
      for (int k4 = 0; k4 < 64; ++k4) {
        float4 xv = xs[k4];
        float4 q0 = e0[k4], q1 = e1[k4], q2 = e2[k4], q3 = e3[k4];
        a0 += (double)xv.x * q0.x + (double)xv.z * q0.z;
        b0 += (double)xv.y * q0.y + (double)xv.w * q0.w;
        a1 += (double)xv.x * q1.x + (double)xv.z * q1.z;
        b1 += (double)xv.y * q1.y + (double)xv.w * q1.w;
        a2 += (double)xv.x * q2.x + (double)xv.z * q2.z;
        b2 += (double)xv.y * q2.y + (double)xv.w * q2.w;
        a3 += (double)xv.x * q3.x + (double)xv.z * q3.z;
        b3 += (double)xv.y * q3.y + (double)xv.w * q3.w;
      }
      double d0 = e2d[v0] - 2.0 * (a0 + b0);
      double d1 = e2d[v0 + 256] - 2.0 * (a1 + b1);
      double d2 = e2d[v0 + 512] - 2.0 * (a2 + b2);
      double d3 = e2d[v0 + 768] - 2.0 * (a3 + b3);
      if (d0 < best || (d0 == best && v0 < bi)) { best = d0; bi = v0; }
      if (d1 < best || (d1 == best && v0 + 256 < bi)) { best = d1; bi = v0 + 256; }
      if (d2 < best || (d2 == best && v0 + 512 < bi)) { best = d2; bi = v0 + 512; }
      if (d3 < best || (d3 == best && v0 + 768 < bi)) { best = d3; bi = v0 + 768; }
    }
    sd[tid] = best;
    si[tid] = bi;
    __syncthreads();
    for (int s = 128; s > 0; s >>= 1) {
      if (tid < s) {
        double ob = sd[tid + s];
        int oi = si[tid + s];
        if (ob < sd[tid] || (ob == sd[tid] && oi < si[tid])) {
          sd[tid] = ob; si[tid] = oi;
        }
      }
      __syncthreads();
    }
    int win = si[0];
    if (tid < 64) {
      float4 v4 = ((const float4*)(E + (size_t)win * 256))[tid];
      ((float4*)(out + (size_t)row * 256))[tid] = v4;
    }
  }
}

// ---- T2 fallback for medium ws (proven): rows [start, n) direct from E ----
__global__ __launch_bounds__(256) void vq_exact_slow(
    const float* __restrict__ x, const float* __restrict__ E,
    const double* __restrict__ e2d, float* __restrict__ out,
    const unsigned* __restrict__ cnt1, const unsigned* __restrict__ list1,
    unsigned start) {
  __shared__ float4 xs[64];
  __shared__ double sd[256];
  __shared__ int si[256];
  unsigned n = *cnt1;
  if (n > LIST_CAP) n = LIST_CAP;
  const int tid = threadIdx.x;
  for (unsigned i = start + blockIdx.x; i < n; i += gridDim.x) {
    unsigned row = list1[i];
    __syncthreads();
    if (tid < 64) xs[tid] = ((const float4*)(x + (size_t)row * 256))[tid];
    __syncthreads();
    double best = 1e300;
    int bi = 1 << 30;
#pragma unroll 1
    for (int jg = 0; jg < 4; ++jg) {
      const int v0 = tid + jg * 1024;
      const float4* e0 = (const float4*)(E + (size_t)v0 * 256);
      const float4* e1 = (const float4*)(E + (size_t)(v0 + 256) * 256);
      const float4* e2 = (const float4*)(E + (size_t)(v0 + 512) * 256);
      const float4* e3 = (const float4*)(E + (size_t)(v0 + 768) * 256);
      double a0 = 0, a1 = 0, a2 = 0, a3 = 0;
      double b0 = 0, b1 = 0, b2 = 0, b3 = 0;
#pragma unroll 4
      for (int k4 = 0; k4 < 64; ++k4) {
        float4 xv = xs[k4];
        float4 q0 = e0[k4], q1 = e1[k4], q2 = e2[k4], q3 = e3[k4];
        a0 += (double)xv.x * q0.x + (double)xv.z * q0.z;
        b0 += (double)xv.y * q0.y + (double)xv.w * q0.w;
        a1 += (double)xv.x * q1.x + (double)xv.z * q1.z;
        b1 += (double)xv.y * q1.y + (double)xv.w * q1.w;
        a2 += (double)xv.x * q2.x + (double)xv.z * q2.z;
        b2 += (double)xv.y * q2.y + (double)xv.w * q2.w;
        a3 += (double)xv.x * q3.x + (double)xv.z * q3.z;
        b3 += (double)xv.y * q3.y + (double)xv.w * q3.w;
      }
      double d0 = e2d[v0] - 2.0 * (a0 + b0);
      double d1 = e2d[v0 + 256] - 2.0 * (a1 + b1);
      double d2 = e2d[v0 + 512] - 2.0 * (a2 + b2);
      double d3 = e2d[v0 + 768] - 2.0 * (a3 + b3);
      if (d0 < best || (d0 == best && v0 < bi)) { best = d0; bi = v0; }
      if (d1 < best || (d1 == best && v0 + 256 < bi)) { best = d1; bi = v0 + 256; }
      if (d2 < best || (d2 == best && v0 + 512 < bi)) { best = d2; bi = v0 + 512; }
      if (d3 < best || (d3 == best && v0 + 768 < bi)) { best = d3; bi = v0 + 768; }
    }
    sd[tid] = best;
    si[tid] = bi;
    __syncthreads();
    for (int s = 128; s > 0; s >>= 1) {
      if (tid < s) {
        double ob = sd[tid + s];
        int oi = si[tid + s];
        if (ob < sd[tid] || (ob == sd[tid] && oi < si[tid])) {
          sd[tid] = ob; si[tid] = oi;
        }
      }
      __syncthreads();
    }
    int win = si[0];
    if (tid < 64) {
      float4 v4 = ((const float4*)(E + (size_t)win * 256))[tid];
      ((float4*)(out + (size_t)row * 256))[tid] = v4;
    }
  }
}

// ---- insurance: exact fp64 scan of ALL rows (only if ws too small) ----
__global__ void scan_all(const float* __restrict__ x,
                         const float* __restrict__ E, float* out) {
  __shared__ double sd[256];
  __shared__ int si[256];
  for (int row = blockIdx.x; row < 32768; row += gridDim.x) {
    const float* xr = x + (size_t)row * 256;
    double best = 1e300;
    int bi = 1 << 30;
    for (int v = threadIdx.x; v < 4096; v += 256) {
      const float* ev = E + (size_t)v * 256;
      double a0 = 0, a1 = 0, a2 = 0, a3 = 0;
      for (int k = 0; k < 256; k += 4) {
        double d0 = (double)xr[k] - (double)ev[k];
        double d1 = (double)xr[k + 1] - (double)ev[k + 1];
        double d2 = (double)xr[k + 2] - (double)ev[k + 2];
        double d3 = (double)xr[k + 3] - (double)ev[k + 3];
        a0 += d0 * d0; a1 += d1 * d1; a2 += d2 * d2; a3 += d3 * d3;
      }
      double d = (a0 + a1) + (a2 + a3);
      if (d < best || (d == best && v < bi)) { best = d; bi = v; }
    }
    sd[threadIdx.x] = best; si[threadIdx.x] = bi;
    __syncthreads();
    for (int s = 128; s > 0; s >>= 1) {
      if ((int)threadIdx.x < s) {
        double ob = sd[threadIdx.x + s];
        int oi = si[threadIdx.x + s];
        if (ob < sd[threadIdx.x] ||
            (ob == sd[threadIdx.x] && oi < si[threadIdx.x])) {
          sd[threadIdx.x] = ob; si[threadIdx.x] = oi;
        }
      }
      __syncthreads();
    }
    int win = si[0];
    __syncthreads();
    out[(size_t)row * 256 + threadIdx.x] = E[(size_t)win * 256 + threadIdx.x];
  }
}

extern "C" void kernel_launch(void* const* d_in, const int* in_sizes, int n_in,
                              void* d_out, int out_size, void* d_ws,
                              size_t ws_size, hipStream_t stream) {
  (void)in_sizes; (void)n_in; (void)out_size;
  const float* x = (const float*)d_in[0];
  const float* E = (const float*)d_in[1];
  float* out = (float*)d_out;
  char* ws = (char*)d_ws;
  // ws: [cnt 64][e2f 16K][e2d 32K][ehi 2M][list1 256K][ET 4M][part 256K][xpack 32M?]
  const size_t XOFF = 64 + 16384 + 32768 + 2097152 + 262144;  // 2408512
  const size_t ET_OFF = XOFF;
  const size_t PART_OFF = ET_OFF + 4194304;
  const size_t NEED_ET = PART_OFF + (size_t)PROWS * 8 * sizeof(Part);  // +256K
  const size_t NEED_BIG = NEED_ET + 33554432;
  if (ws_size < XOFF) {
    scan_all<<<2048, 256, 0, stream>>>(x, E, out);
    return;
  }
  unsigned* cnt1 = (unsigned*)ws;
  float* e2f = (float*)(ws + 64);
  double* e2d = (double*)(ws + 64 + 16384);
  char* ehi = ws + 64 + 16384 + 32768;
  unsigned* list1 = (unsigned*)(ehi + 2097152);
  char* xpack = (ws_size >= NEED_BIG) ? (ws + NEED_ET) : (char*)d_out;

  if (ws_size >= NEED_ET) {
    float* ETp = (float*)(ws + ET_OFF);
    Part* partp = (Part*)(ws + PART_OFF);
    fused_pack<<<2560, 256, 0, stream>>>(x, xpack, E, ehi, e2f, e2d, ETp, 1,
                                         cnt1);
    vq_main<<<512, 256, 65536, stream>>>(xpack, ehi, e2f, E, out, cnt1, list1);
    vq_exact_part<<<2048, 256, 0, stream>>>(x, ETp, e2d, partp, cnt1, list1);
    vq_combine2<<<256, 256, 0, stream>>>(partp, x, E, e2d, cnt1, list1, out);
  } else {
    fused_pack<<<2560, 256, 0, stream>>>(x, xpack, E, ehi, e2f, e2d, nullptr,
                                         0, cnt1);
    vq_main<<<512, 256, 65536, stream>>>(xpack, ehi, e2f, E, out, cnt1, list1);
    vq_exact_slow<<<1024, 256, 0, stream>>>(x, E, e2d, out, cnt1, list1, 0u);
  }
}